// Round 1
// 709.977 us; speedup vs baseline: 1.0294x; 1.0294x over previous
//
#include <hip/hip_runtime.h>
#include <hip/hip_bf16.h>
#include <stdint.h>

typedef __attribute__((ext_vector_type(8))) short bf16x8;
typedef __attribute__((ext_vector_type(4))) float f32x4;
typedef __attribute__((ext_vector_type(4))) unsigned short ushort4_t;

__device__ __forceinline__ unsigned short f2bf(float f) {
  union { float f; unsigned int i; } x; x.f = f;
  return (unsigned short)((x.i + 0x7fffu + ((x.i >> 16) & 1u)) >> 16);
}

// async global->LDS, 16B per lane; LDS dest is wave-uniform base + lane*16
__device__ __forceinline__ void gl_lds16(const void* g, void* l) {
  __builtin_amdgcn_global_load_lds(
      (const __attribute__((address_space(1))) unsigned int*)(uintptr_t)g,
      (__attribute__((address_space(3))) unsigned int*)(uint32_t)(uintptr_t)l,
      16, 0, 0);
}

// raw barrier (no vmcnt/lgkmcnt drain!) with compiler memory fences so LDS
// reads/writes and global_load_lds issues cannot be moved across it.
__device__ __forceinline__ void bar() {
  asm volatile("" ::: "memory");
  __builtin_amdgcn_s_barrier();
  asm volatile("" ::: "memory");
}

// inv_freq[j] = 10000^(-j/16), j = 0..15 (d_half=32, 16 freqs)
__constant__ float INVF[16] = {
  1.0f,   0.56234132519f,  0.31622776601f,  0.17782794100f,
  0.1f,   0.056234132519f, 0.031622776601f, 0.017782794100f,
  0.01f,  0.0056234132519f,0.0031622776601f,0.0017782794100f,
  0.001f, 0.00056234132519f,0.00031622776601f,0.00017782794100f
};

// ---- fp32 -> bf16 bulk convert (x) ----
__global__ __launch_bounds__(256) void k_conv_x(const float4* __restrict__ src,
                                                ushort4_t* __restrict__ dst, int n4) {
  int i = blockIdx.x * 256 + threadIdx.x;
  if (i < n4) {
    float4 v = src[i];
    ushort4_t r = { f2bf(v.x), f2bf(v.y), f2bf(v.z), f2bf(v.w) };
    dst[i] = r;
  }
}

// ---- fp32 RxC -> bf16 CxR transpose (weights to B^T layout) ----
__global__ __launch_bounds__(256) void k_transpose_bf16(const float* __restrict__ src,
                                                        unsigned short* __restrict__ dst,
                                                        int R, int C) {
  __shared__ unsigned short tile[64][65];
  const int bj = blockIdx.x, bi = blockIdx.y;
  const int t = threadIdx.x, lr = t >> 6, lc = t & 63;
  #pragma unroll
  for (int i = 0; i < 16; i++) {
    int r = i * 4 + lr;
    tile[r][lc] = f2bf(src[(size_t)(bi * 64 + r) * C + bj * 64 + lc]);
  }
  __syncthreads();
  #pragma unroll
  for (int i = 0; i < 16; i++) {
    int r = i * 4 + lr;
    dst[(size_t)(bj * 64 + r) * R + bi * 64 + lc] = tile[lc][r];
  }
}

// ---- Pipelined GEMM: C[M,N] = A[M,K] * B[N,K]^T, bf16 in, bf16 or f32(+bias) out
//
// BM=256, BN=128, BK=64. 512 threads = 8 waves (4M x 2N), 64x64 output per wave.
// LDS: 3 slots x (A 256x64 + B 128x64) bf16 = 144 KB, rotating c -> slot c%3.
// Deep pipeline (T3+T4): while computing chunk c (slot c%3) we stage chunk c+2
// into slot (c+2)%3 (free: chunk c-1 finished last iteration). One counted
// s_waitcnt vmcnt(6) per chunk (6 = chunk c+2's in-flight loads), raw s_barrier
// only -- the vmcnt(0) drain of __syncthreads is what capped the old structure.
// Correctness of cross-wave visibility: every wave issues its staging loads in
// the same phase pattern; per-wave in-order vmcnt(6) before the end-of-chunk
// barrier retires exactly the previous chunk's 6 loads, so after the barrier
// chunk c+1 is fully in LDS for ALL waves. Slot (c+2)%3 overwrite is safe
// because chunk c-1's last ds_reads completed before each wave's lgkmcnt(0)
// which precedes the barrier every wave passed before issuing the stores.
// XOR chunk swizzle (LDS chunk t of row r holds global chunk t^(r&7), via
// pre-swizzled global source) -- conflict-free ds_read_b128, PMC-verified 0.
// ROPE=1: fused 2D-RoPE epilogue on the q/k cols (wave's 64-col group = 1 head).
template<int F32OUT, int ROPE>
__global__ __launch_bounds__(512, 1) void k_gemm_bt(
    const unsigned short* __restrict__ A, const unsigned short* __restrict__ B,
    unsigned short* __restrict__ Cb, float* __restrict__ Cf,
    const float* __restrict__ bias, int M, int N, int K) {
  __shared__ __align__(16) unsigned short As[3 * 256 * 64];  // 96 KB
  __shared__ __align__(16) unsigned short Bs[3 * 128 * 64];  // 48 KB
  const int tid = threadIdx.x;
  const int lane = tid & 63, wid = tid >> 6;
  const int cl = lane & 15, gr = lane >> 4;
  const int wm = wid >> 1, wn = wid & 1;
  const int l8 = lane >> 3, l7 = lane & 7;
  const int mBase = blockIdx.y * 256, nBase = blockIdx.x * 128;
  const int KT = K >> 6;                 // 64-wide K chunks (16 here)
  const int ldsW = (wid * 8) * 64;       // wave-uniform LDS row-base offset

  // per-thread global source pointers (include row and pre-swizzled chunk)
  const unsigned short* aP[4];
  const unsigned short* bP[2];
  #pragma unroll
  for (int i = 0; i < 4; i++)
    aP[i] = A + (size_t)(mBase + i * 64 + wid * 8 + l8) * K + (l7 ^ l8) * 8;
  #pragma unroll
  for (int i = 0; i < 2; i++)
    bP[i] = B + (size_t)(nBase + i * 64 + wid * 8 + l8) * K + (l7 ^ l8) * 8;

  const f32x4 zero4 = {0.f, 0.f, 0.f, 0.f};
  f32x4 acc[4][4];
  #pragma unroll
  for (int a = 0; a < 4; a++)
    #pragma unroll
    for (int b = 0; b < 4; b++) acc[a][b] = zero4;

  // prologue: chunk 0 -> slot 0, chunk 1 -> slot 1 (6 loads each, in order)
  #pragma unroll
  for (int i = 0; i < 4; i++) gl_lds16(aP[i], &As[(i * 64) * 64 + ldsW]);
  #pragma unroll
  for (int i = 0; i < 2; i++) gl_lds16(bP[i], &Bs[(i * 64) * 64 + ldsW]);
  #pragma unroll
  for (int i = 0; i < 4; i++) gl_lds16(aP[i] + 64, &As[16384 + (i * 64) * 64 + ldsW]);
  #pragma unroll
  for (int i = 0; i < 2; i++) gl_lds16(bP[i] + 64, &Bs[8192 + (i * 64) * 64 + ldsW]);
  asm volatile("s_waitcnt vmcnt(6)" ::: "memory");  // chunk 0 landed, chunk 1 in flight
  bar();

  for (int c = 0; c < KT; ++c) {
    const int s = c % 3;
    const int sn = (c + 2) % 3;
    const unsigned short* as_ = As + s * 16384;
    const unsigned short* bs_ = Bs + s * 8192;
    const bool pf = (c + 2 < KT);

    #pragma unroll
    for (int kc = 0; kc < 2; ++kc) {
      // phase kc: ds-read this phase's fragments ...
      bf16x8 af[4], bfv[4];
      const int coff = ((kc * 4 + gr) ^ (cl & 7)) * 8;
      #pragma unroll
      for (int t = 0; t < 4; t++) {
        af[t]  = *(const bf16x8*)&as_[(wm * 64 + t * 16 + cl) * 64 + coff];
        bfv[t] = *(const bf16x8*)&bs_[(wn * 64 + t * 16 + cl) * 64 + coff];
      }
      // ... and issue half of chunk c+2's staging (3 loads/phase, 6/chunk)
      if (pf) {
        const int koff = (c + 2) * 64;
        if (kc == 0) {
          gl_lds16(aP[0] + koff, &As[sn * 16384 + (0 * 64) * 64 + ldsW]);
          gl_lds16(aP[1] + koff, &As[sn * 16384 + (1 * 64) * 64 + ldsW]);
          gl_lds16(aP[2] + koff, &As[sn * 16384 + (2 * 64) * 64 + ldsW]);
        } else {
          gl_lds16(aP[3] + koff, &As[sn * 16384 + (3 * 64) * 64 + ldsW]);
          gl_lds16(bP[0] + koff, &Bs[sn * 8192 + (0 * 64) * 64 + ldsW]);
          gl_lds16(bP[1] + koff, &Bs[sn * 8192 + (1 * 64) * 64 + ldsW]);
        }
      }
      bar();
      asm volatile("s_waitcnt lgkmcnt(0)" ::: "memory");
      __builtin_amdgcn_s_setprio(1);
      #pragma unroll
      for (int mt = 0; mt < 4; mt++)
        #pragma unroll
        for (int nt = 0; nt < 4; nt++)
          acc[mt][nt] = __builtin_amdgcn_mfma_f32_16x16x32_bf16(af[mt], bfv[nt], acc[mt][nt], 0, 0, 0);
      __builtin_amdgcn_s_setprio(0);
      if (kc == 0) {
        bar();  // end of phase A
      } else {
        // end of chunk: retire chunk c+1's 6 loads, keep chunk c+2's 6 in flight
        if (c + 2 < KT)      asm volatile("s_waitcnt vmcnt(6)" ::: "memory");
        else if (c + 1 < KT) asm volatile("s_waitcnt vmcnt(0)" ::: "memory");
        if (c + 1 < KT) bar();
      }
    }
  }

  if (ROPE && nBase < 2048) {  // q or k region of qkv output (wave-uniform)
    const float f = INVF[cl];
    #pragma unroll
    for (int mt = 0; mt < 4; mt++)
      #pragma unroll
      for (int r = 0; r < 4; r++) {
        const int sp = (mBase + wm * 64 + mt * 16 + gr * 4 + r) & 255;
        float sh, ch, sw, cw;
        __sincosf((float)(sp >> 4) * f, &sh, &ch);
        __sincosf((float)(sp & 15) * f, &sw, &cw);
        const float a = acc[mt][0][r], b = acc[mt][1][r];
        const float cc = acc[mt][2][r], d = acc[mt][3][r];
        acc[mt][0][r] = a * ch - b * sh;
        acc[mt][1][r] = b * ch + a * sh;
        acc[mt][2][r] = cc * cw - d * sw;
        acc[mt][3][r] = d * cw + cc * sw;
      }
  }

  // C/D layout (m89-verified): col = lane&15, row = (lane>>4)*4 + reg
  #pragma unroll
  for (int mt = 0; mt < 4; mt++)
    #pragma unroll
    for (int nt = 0; nt < 4; nt++)
      #pragma unroll
      for (int r = 0; r < 4; r++) {
        const int row = mBase + wm * 64 + mt * 16 + gr * 4 + r;
        const int col = nBase + wn * 64 + nt * 16 + cl;
        const float v = acc[mt][nt][r];
        if (F32OUT) Cf[(size_t)row * N + col] = v + bias[col];
        else        Cb[(size_t)row * N + col] = f2bf(v);
      }
}

// ---- flash attention (RoPE pre-applied): one block per (n, head); 4 waves x 64 q
// (unchanged this round -- see journal; GEMM pipeline is the experiment)
__global__ __launch_bounds__(256, 3) void k_attn(const unsigned short* __restrict__ qkv,
                                                 unsigned short* __restrict__ attn_out) {
  __shared__ __align__(16) unsigned short Qp[4][64 * 64];  // per-wave Q, then P
  __shared__ __align__(16) unsigned short Kt[64 * 64];
  __shared__ __align__(16) unsigned short Vt[64 * 64];     // V^T, pi-permuted cols
  const int blk = blockIdx.x;
  const int n = blk >> 4, h = blk & 15;
  const int tid = threadIdx.x;
  const int lane = tid & 63, wid = tid >> 6;
  const int cl = lane & 15, gr = lane >> 4;
  const int l8 = lane >> 3, l7 = lane & 7;
  const unsigned short* qbase = qkv + (size_t)n * 256 * 3072 + h * 64;
  const unsigned short* kbase = qbase + 1024;
  const unsigned short* vbase = qbase + 2048;

  #pragma unroll
  for (int i = 0; i < 8; i++)
    gl_lds16(qbase + (size_t)(wid * 64 + i * 8 + l8) * 3072 + (l7 ^ l8) * 8,
             &Qp[wid][i * 8 * 64]);
  #pragma unroll
  for (int i = 0; i < 2; i++) {
    const int r0 = (wid * 2 + i) * 8;
    gl_lds16(kbase + (size_t)(r0 + l8) * 3072 + (l7 ^ l8) * 8, &Kt[r0 * 64]);
  }

  unsigned int vr[2][4];
  #pragma unroll
  for (int i = 0; i < 2; i++) {
    const int u = i * 256 + tid;
    const int t0 = u >> 5, d = (u & 31) * 2;
    #pragma unroll
    for (int k = 0; k < 4; k++)
      vr[i][k] = *(const unsigned int*)(vbase + (size_t)(t0 + 16 * k) * 3072 + d);
  }
  __syncthreads();

  bf16x8 qf[4][2];
  #pragma unroll
  for (int mt = 0; mt < 4; mt++)
    #pragma unroll
    for (int kc = 0; kc < 2; kc++)
      qf[mt][kc] = *(const bf16x8*)&Qp[wid][(mt * 16 + cl) * 64 + ((kc * 4 + gr) ^ (cl & 7)) * 8];

  const f32x4 zero4 = {0.f, 0.f, 0.f, 0.f};
  f32x4 o[4][4];
  float lsum[4][4];
  #pragma unroll
  for (int a = 0; a < 4; a++)
    #pragma unroll
    for (int b = 0; b < 4; b++) { o[a][b] = zero4; lsum[a][b] = 0.f; }

  for (int tc = 0; tc < 4; tc++) {
    #pragma unroll
    for (int i = 0; i < 2; i++) {
      const int u = i * 256 + tid;
      const int t0 = u >> 5, d = (u & 31) * 2;
      const unsigned int r0 = vr[i][0], r1 = vr[i][1], r2 = vr[i][2], r3 = vr[i][3];
      uint2 lo, hi;
      lo.x = (r0 & 0xffffu) | (r1 << 16);
      lo.y = (r2 & 0xffffu) | (r3 << 16);
      hi.x = (r0 >> 16) | (r1 & 0xffff0000u);
      hi.y = (r2 >> 16) | (r3 & 0xffff0000u);
      *(uint2*)&Vt[d * 64 + ((t0 >> 1) ^ (d & 7)) * 8 + (t0 & 1) * 4] = lo;
      const int d1 = d + 1;
      *(uint2*)&Vt[d1 * 64 + ((t0 >> 1) ^ (d1 & 7)) * 8 + (t0 & 1) * 4] = hi;
    }
    if (tc < 3) {
      #pragma unroll
      for (int i = 0; i < 2; i++) {
        const int u = i * 256 + tid;
        const int t0 = u >> 5, d = (u & 31) * 2;
        #pragma unroll
        for (int k = 0; k < 4; k++)
          vr[i][k] = *(const unsigned int*)(vbase + (size_t)((tc + 1) * 64 + t0 + 16 * k) * 3072 + d);
      }
    }

    #pragma unroll
    for (int mt = 0; mt < 4; mt++) {
      f32x4 sacc[4] = {zero4, zero4, zero4, zero4};
      #pragma unroll
      for (int kc = 0; kc < 2; kc++)
        #pragma unroll
        for (int nt = 0; nt < 4; nt++) {
          const bf16x8 kf = *(const bf16x8*)&Kt[(nt * 16 + cl) * 64 + ((kc * 4 + gr) ^ (cl & 7)) * 8];
          sacc[nt] = __builtin_amdgcn_mfma_f32_16x16x32_bf16(qf[mt][kc], kf, sacc[nt], 0, 0, 0);
        }
      #pragma unroll
      for (int r = 0; r < 4; r++) {
        const float p0 = __expf(sacc[0][r] * 0.125f);
        const float p1 = __expf(sacc[1][r] * 0.125f);
        const float p2 = __expf(sacc[2][r] * 0.125f);
        const float p3 = __expf(sacc[3][r] * 0.125f);
        lsum[mt][r] += (p0 + p1) + (p2 + p3);
        float2 f01; f01.x = p0; f01.y = p1;
        float2 f23; f23.x = p2; f23.y = p3;
        __hip_bfloat162 b01 = __float22bfloat162_rn(f01);
        __hip_bfloat162 b23 = __float22bfloat162_rn(f23);
        union { __hip_bfloat162 h; unsigned int u; } c0, c1;
        c0.h = b01; c1.h = b23;
        uint2 w; w.x = c0.u; w.y = c1.u;
        const int m = mt * 16 + gr * 4 + r;
        *(uint2*)&Qp[wid][m * 64 + ((cl >> 1) ^ (m & 7)) * 8 + (cl & 1) * 4] = w;
      }
    }
    __syncthreads();

    if (tc < 3) {
      #pragma unroll
      for (int i = 0; i < 2; i++) {
        const int r0 = (wid * 2 + i) * 8;
        gl_lds16(kbase + (size_t)((tc + 1) * 64 + r0 + l8) * 3072 + (l7 ^ l8) * 8, &Kt[r0 * 64]);
      }
    }

    #pragma unroll
    for (int kc = 0; kc < 2; kc++) {
      bf16x8 vf[4], pf[4];
      #pragma unroll
      for (int dt = 0; dt < 4; dt++)
        vf[dt] = *(const bf16x8*)&Vt[(dt * 16 + cl) * 64 + ((kc * 4 + gr) ^ (cl & 7)) * 8];
      #pragma unroll
      for (int mt = 0; mt < 4; mt++)
        pf[mt] = *(const bf16x8*)&Qp[wid][(mt * 16 + cl) * 64 + ((kc * 4 + gr) ^ (cl & 7)) * 8];
      #pragma unroll
      for (int mt = 0; mt < 4; mt++)
        #pragma unroll
        for (int dt = 0; dt < 4; dt++)
          o[mt][dt] = __builtin_amdgcn_mfma_f32_16x16x32_bf16(pf[mt], vf[dt], o[mt][dt], 0, 0, 0);
    }
    __syncthreads();
  }

  #pragma unroll
  for (int mt = 0; mt < 4; mt++)
    #pragma unroll
    for (int r = 0; r < 4; r++) {
      float l = lsum[mt][r];
      l += __shfl_xor(l, 1);
      l += __shfl_xor(l, 2);
      l += __shfl_xor(l, 4);
      l += __shfl_xor(l, 8);
      const float inv = 1.0f / l;
      const int srow = wid * 64 + mt * 16 + gr * 4 + r;
      #pragma unroll
      for (int dt = 0; dt < 4; dt++)
        attn_out[(size_t)(n * 256 + srow) * 1024 + h * 64 + dt * 16 + cl] =
            f2bf(o[mt][dt][r] * inv);
    }
}

extern "C" void kernel_launch(void* const* d_in, const int* in_sizes, int n_in,
                              void* d_out, int out_size, void* d_ws, size_t ws_size,
                              hipStream_t stream) {
  const float* x      = (const float*)d_in[0];   // (4,32,16,16,1024)
  const float* w_qkv  = (const float*)d_in[1];   // (1024,3072)
  const float* w_proj = (const float*)d_in[2];   // (1024,1024)
  const float* b_proj = (const float*)d_in[3];   // (1024,)
  float* out = (float*)d_out;
  char* ws = (char*)d_ws;

  unsigned short* x_bf    = (unsigned short*)ws;                // 64 MiB (reused as attn out)
  unsigned short* wqkvT   = (unsigned short*)(ws + 67108864);   // [3072][1024]
  unsigned short* wprojT  = (unsigned short*)(ws + 73400320);   // [1024][1024]
  unsigned short* qkvb    = (unsigned short*)(ws + 75497472);   // [32768][3072]
  unsigned short* attn_bf = x_bf;

  k_conv_x<<<32768, 256, 0, stream>>>((const float4*)x, (ushort4_t*)x_bf, 8388608);
  k_transpose_bf16<<<dim3(48, 16), 256, 0, stream>>>(w_qkv, wqkvT, 1024, 3072);
  k_transpose_bf16<<<dim3(16, 16), 256, 0, stream>>>(w_proj, wprojT, 1024, 1024);

  // qkv = x @ w_qkv with fused 2D-RoPE on q,k (M=32768, N=3072, K=1024)
  k_gemm_bt<0, 1><<<dim3(24, 128), 512, 0, stream>>>(x_bf, wqkvT, qkvb, nullptr, nullptr,
                                                     32768, 3072, 1024);
  // flash attention, one block per (n, head)
  k_attn<<<2048, 256, 0, stream>>>(qkvb, attn_bf);

  // out = attn @ w_proj + b_proj (M=32768, N=1024, K=1024)
  k_gemm_bt<1, 0><<<dim3(8, 128), 512, 0, stream>>>(attn_bf, wprojT, nullptr, out, b_proj,
                                                    32768, 1024, 1024);
}

// Round 2
// 704.731 us; speedup vs baseline: 1.0371x; 1.0074x over previous
//
#include <hip/hip_runtime.h>
#include <hip/hip_bf16.h>
#include <stdint.h>

typedef __attribute__((ext_vector_type(8))) short bf16x8;
typedef __attribute__((ext_vector_type(4))) float f32x4;
typedef __attribute__((ext_vector_type(4))) unsigned short ushort4_t;

__device__ __forceinline__ unsigned short f2bf(float f) {
  union { float f; unsigned int i; } x; x.f = f;
  return (unsigned short)((x.i + 0x7fffu + ((x.i >> 16) & 1u)) >> 16);
}

// async global->LDS, 16B per lane; LDS dest is wave-uniform base + lane*16
__device__ __forceinline__ void gl_lds16(const void* g, void* l) {
  __builtin_amdgcn_global_load_lds(
      (const __attribute__((address_space(1))) unsigned int*)(uintptr_t)g,
      (__attribute__((address_space(3))) unsigned int*)(uint32_t)(uintptr_t)l,
      16, 0, 0);
}

// raw barrier (no vmcnt/lgkmcnt drain!) with compiler memory fences so LDS
// reads/writes and global_load_lds issues cannot be moved across it.
__device__ __forceinline__ void bar() {
  asm volatile("" ::: "memory");
  __builtin_amdgcn_s_barrier();
  asm volatile("" ::: "memory");
}

// inv_freq[j] = 10000^(-j/16), j = 0..15 (d_half=32, 16 freqs)
__constant__ float INVF[16] = {
  1.0f,   0.56234132519f,  0.31622776601f,  0.17782794100f,
  0.1f,   0.056234132519f, 0.031622776601f, 0.017782794100f,
  0.01f,  0.0056234132519f,0.0031622776601f,0.0017782794100f,
  0.001f, 0.00056234132519f,0.00031622776601f,0.00017782794100f
};

// ---- fp32 -> bf16 bulk convert (x) ----
__global__ __launch_bounds__(256) void k_conv_x(const float4* __restrict__ src,
                                                ushort4_t* __restrict__ dst, int n4) {
  int i = blockIdx.x * 256 + threadIdx.x;
  if (i < n4) {
    float4 v = src[i];
    ushort4_t r = { f2bf(v.x), f2bf(v.y), f2bf(v.z), f2bf(v.w) };
    dst[i] = r;
  }
}

// ---- fp32 RxC -> bf16 CxR transpose (weights to B^T layout) ----
__global__ __launch_bounds__(256) void k_transpose_bf16(const float* __restrict__ src,
                                                        unsigned short* __restrict__ dst,
                                                        int R, int C) {
  __shared__ unsigned short tile[64][65];
  const int bj = blockIdx.x, bi = blockIdx.y;
  const int t = threadIdx.x, lr = t >> 6, lc = t & 63;
  #pragma unroll
  for (int i = 0; i < 16; i++) {
    int r = i * 4 + lr;
    tile[r][lc] = f2bf(src[(size_t)(bi * 64 + r) * C + bj * 64 + lc]);
  }
  __syncthreads();
  #pragma unroll
  for (int i = 0; i < 16; i++) {
    int r = i * 4 + lr;
    dst[(size_t)(bj * 64 + r) * R + bi * 64 + lc] = tile[lc][r];
  }
}

// ---- Pipelined GEMM: C[M,N] = A[M,K] * B[N,K]^T, bf16 in, bf16 or f32(+bias) out
//
// BM=256, BN=128, BK=64. 512 threads = 8 waves (4M x 2N), 64x64 output per wave.
// LDS: 3 slots x (A 256x64 + B 128x64) bf16 = 144 KB, rotating c -> slot c%3.
//
// R2 schedule: ONE barrier per chunk (was 4). Intra-chunk barriers were only
// pacing, not correctness: both phases read the SAME slot, and all slot-ring
// hazards are covered by the end-of-chunk vmcnt(6)+barrier (per-wave in-order
// vmcnt retires chunk c+1's stages on every wave before the barrier; staging
// chunk c+2 overwrites slot (c-1)%3 whose reads completed before every wave's
// previous end-of-chunk barrier). Both phases' fragment ds_reads + all 6 stage
// issues go up front as plain C loads: the compiler emits counted lgkmcnt so
// MFMA(kc0) starts when its 8 reads land while kc1's 8 remain in flight under
// it -- LDS-read burst overlaps the MFMA pipe instead of serializing with it.
// XOR chunk swizzle (LDS chunk t of row r holds global chunk t^(r&7), via
// pre-swizzled global source) -- conflict-free ds_read_b128, PMC-verified 0.
// ROPE=1: fused 2D-RoPE epilogue on the q/k cols (wave's 64-col group = 1 head).
template<int F32OUT, int ROPE>
__global__ __launch_bounds__(512, 1) void k_gemm_bt(
    const unsigned short* __restrict__ A, const unsigned short* __restrict__ B,
    unsigned short* __restrict__ Cb, float* __restrict__ Cf,
    const float* __restrict__ bias, int M, int N, int K) {
  __shared__ __align__(16) unsigned short As[3 * 256 * 64];  // 96 KB
  __shared__ __align__(16) unsigned short Bs[3 * 128 * 64];  // 48 KB
  const int tid = threadIdx.x;
  const int lane = tid & 63, wid = tid >> 6;
  const int cl = lane & 15, gr = lane >> 4;
  const int wm = wid >> 1, wn = wid & 1;
  const int l8 = lane >> 3, l7 = lane & 7;
  const int mBase = blockIdx.y * 256, nBase = blockIdx.x * 128;
  const int KT = K >> 6;                 // 64-wide K chunks (16 here)
  const int ldsW = (wid * 8) * 64;       // wave-uniform LDS row-base offset

  // per-thread global source pointers (include row and pre-swizzled chunk)
  const unsigned short* aP[4];
  const unsigned short* bP[2];
  #pragma unroll
  for (int i = 0; i < 4; i++)
    aP[i] = A + (size_t)(mBase + i * 64 + wid * 8 + l8) * K + (l7 ^ l8) * 8;
  #pragma unroll
  for (int i = 0; i < 2; i++)
    bP[i] = B + (size_t)(nBase + i * 64 + wid * 8 + l8) * K + (l7 ^ l8) * 8;

  const f32x4 zero4 = {0.f, 0.f, 0.f, 0.f};
  f32x4 acc[4][4];
  #pragma unroll
  for (int a = 0; a < 4; a++)
    #pragma unroll
    for (int b = 0; b < 4; b++) acc[a][b] = zero4;

  // prologue: chunk 0 -> slot 0, chunk 1 -> slot 1 (6 loads each, in order)
  #pragma unroll
  for (int i = 0; i < 4; i++) gl_lds16(aP[i], &As[(i * 64) * 64 + ldsW]);
  #pragma unroll
  for (int i = 0; i < 2; i++) gl_lds16(bP[i], &Bs[(i * 64) * 64 + ldsW]);
  #pragma unroll
  for (int i = 0; i < 4; i++) gl_lds16(aP[i] + 64, &As[16384 + (i * 64) * 64 + ldsW]);
  #pragma unroll
  for (int i = 0; i < 2; i++) gl_lds16(bP[i] + 64, &Bs[8192 + (i * 64) * 64 + ldsW]);
  asm volatile("s_waitcnt vmcnt(6)" ::: "memory");  // chunk 0 landed, chunk 1 in flight
  bar();

  for (int c = 0; c < KT; ++c) {
    const int s = c % 3;
    const int sn = (c + 2) % 3;
    const unsigned short* as_ = As + s * 16384;
    const unsigned short* bs_ = Bs + s * 8192;

    // both phases' fragment reads, issued up front (plain loads: compiler
    // emits counted lgkmcnt -- MFMA(kc0) starts with kc1 reads in flight)
    const int c0 = ((0 * 4 + gr) ^ (cl & 7)) * 8;
    const int c1 = ((1 * 4 + gr) ^ (cl & 7)) * 8;
    bf16x8 af0[4], bv0[4], af1[4], bv1[4];
    #pragma unroll
    for (int t = 0; t < 4; t++) {
      af0[t] = *(const bf16x8*)&as_[(wm * 64 + t * 16 + cl) * 64 + c0];
      bv0[t] = *(const bf16x8*)&bs_[(wn * 64 + t * 16 + cl) * 64 + c0];
    }
    #pragma unroll
    for (int t = 0; t < 4; t++) {
      af1[t] = *(const bf16x8*)&as_[(wm * 64 + t * 16 + cl) * 64 + c1];
      bv1[t] = *(const bf16x8*)&bs_[(wn * 64 + t * 16 + cl) * 64 + c1];
    }
    // stage chunk c+2 into slot sn (6 loads; vmcnt ops, independent of lgkm)
    if (c + 2 < KT) {
      const int koff = (c + 2) * 64;
      gl_lds16(aP[0] + koff, &As[sn * 16384 + (0 * 64) * 64 + ldsW]);
      gl_lds16(aP[1] + koff, &As[sn * 16384 + (1 * 64) * 64 + ldsW]);
      gl_lds16(aP[2] + koff, &As[sn * 16384 + (2 * 64) * 64 + ldsW]);
      gl_lds16(aP[3] + koff, &As[sn * 16384 + (3 * 64) * 64 + ldsW]);
      gl_lds16(bP[0] + koff, &Bs[sn * 8192 + (0 * 64) * 64 + ldsW]);
      gl_lds16(bP[1] + koff, &Bs[sn * 8192 + (1 * 64) * 64 + ldsW]);
    }

    __builtin_amdgcn_s_setprio(1);
    #pragma unroll
    for (int mt = 0; mt < 4; mt++)
      #pragma unroll
      for (int nt = 0; nt < 4; nt++)
        acc[mt][nt] = __builtin_amdgcn_mfma_f32_16x16x32_bf16(af0[mt], bv0[nt], acc[mt][nt], 0, 0, 0);
    #pragma unroll
    for (int mt = 0; mt < 4; mt++)
      #pragma unroll
      for (int nt = 0; nt < 4; nt++)
        acc[mt][nt] = __builtin_amdgcn_mfma_f32_16x16x32_bf16(af1[mt], bv1[nt], acc[mt][nt], 0, 0, 0);
    __builtin_amdgcn_s_setprio(0);

    // end of chunk: retire chunk c+1's 6 loads, keep chunk c+2's 6 in flight
    if (c + 2 < KT)      asm volatile("s_waitcnt vmcnt(6)" ::: "memory");
    else if (c + 1 < KT) asm volatile("s_waitcnt vmcnt(0)" ::: "memory");
    if (c + 1 < KT) bar();
  }

  if (ROPE && nBase < 2048) {  // q or k region of qkv output (wave-uniform)
    const float f = INVF[cl];
    #pragma unroll
    for (int mt = 0; mt < 4; mt++)
      #pragma unroll
      for (int r = 0; r < 4; r++) {
        const int sp = (mBase + wm * 64 + mt * 16 + gr * 4 + r) & 255;
        float sh, ch, sw, cw;
        __sincosf((float)(sp >> 4) * f, &sh, &ch);
        __sincosf((float)(sp & 15) * f, &sw, &cw);
        const float a = acc[mt][0][r], b = acc[mt][1][r];
        const float cc = acc[mt][2][r], d = acc[mt][3][r];
        acc[mt][0][r] = a * ch - b * sh;
        acc[mt][1][r] = b * ch + a * sh;
        acc[mt][2][r] = cc * cw - d * sw;
        acc[mt][3][r] = d * cw + cc * sw;
      }
  }

  // C/D layout (m89-verified): col = lane&15, row = (lane>>4)*4 + reg
  #pragma unroll
  for (int mt = 0; mt < 4; mt++)
    #pragma unroll
    for (int nt = 0; nt < 4; nt++)
      #pragma unroll
      for (int r = 0; r < 4; r++) {
        const int row = mBase + wm * 64 + mt * 16 + gr * 4 + r;
        const int col = nBase + wn * 64 + nt * 16 + cl;
        const float v = acc[mt][nt][r];
        if (F32OUT) Cf[(size_t)row * N + col] = v + bias[col];
        else        Cb[(size_t)row * N + col] = f2bf(v);
      }
}

// ---- flash attention (RoPE pre-applied): one block per (n, head); 4 waves x 64 q
// (unchanged this round -- GEMM schedule is the experiment)
__global__ __launch_bounds__(256, 3) void k_attn(const unsigned short* __restrict__ qkv,
                                                 unsigned short* __restrict__ attn_out) {
  __shared__ __align__(16) unsigned short Qp[4][64 * 64];  // per-wave Q, then P
  __shared__ __align__(16) unsigned short Kt[64 * 64];
  __shared__ __align__(16) unsigned short Vt[64 * 64];     // V^T, pi-permuted cols
  const int blk = blockIdx.x;
  const int n = blk >> 4, h = blk & 15;
  const int tid = threadIdx.x;
  const int lane = tid & 63, wid = tid >> 6;
  const int cl = lane & 15, gr = lane >> 4;
  const int l8 = lane >> 3, l7 = lane & 7;
  const unsigned short* qbase = qkv + (size_t)n * 256 * 3072 + h * 64;
  const unsigned short* kbase = qbase + 1024;
  const unsigned short* vbase = qbase + 2048;

  #pragma unroll
  for (int i = 0; i < 8; i++)
    gl_lds16(qbase + (size_t)(wid * 64 + i * 8 + l8) * 3072 + (l7 ^ l8) * 8,
             &Qp[wid][i * 8 * 64]);
  #pragma unroll
  for (int i = 0; i < 2; i++) {
    const int r0 = (wid * 2 + i) * 8;
    gl_lds16(kbase + (size_t)(r0 + l8) * 3072 + (l7 ^ l8) * 8, &Kt[r0 * 64]);
  }

  unsigned int vr[2][4];
  #pragma unroll
  for (int i = 0; i < 2; i++) {
    const int u = i * 256 + tid;
    const int t0 = u >> 5, d = (u & 31) * 2;
    #pragma unroll
    for (int k = 0; k < 4; k++)
      vr[i][k] = *(const unsigned int*)(vbase + (size_t)(t0 + 16 * k) * 3072 + d);
  }
  __syncthreads();

  bf16x8 qf[4][2];
  #pragma unroll
  for (int mt = 0; mt < 4; mt++)
    #pragma unroll
    for (int kc = 0; kc < 2; kc++)
      qf[mt][kc] = *(const bf16x8*)&Qp[wid][(mt * 16 + cl) * 64 + ((kc * 4 + gr) ^ (cl & 7)) * 8];

  const f32x4 zero4 = {0.f, 0.f, 0.f, 0.f};
  f32x4 o[4][4];
  float lsum[4][4];
  #pragma unroll
  for (int a = 0; a < 4; a++)
    #pragma unroll
    for (int b = 0; b < 4; b++) { o[a][b] = zero4; lsum[a][b] = 0.f; }

  for (int tc = 0; tc < 4; tc++) {
    #pragma unroll
    for (int i = 0; i < 2; i++) {
      const int u = i * 256 + tid;
      const int t0 = u >> 5, d = (u & 31) * 2;
      const unsigned int r0 = vr[i][0], r1 = vr[i][1], r2 = vr[i][2], r3 = vr[i][3];
      uint2 lo, hi;
      lo.x = (r0 & 0xffffu) | (r1 << 16);
      lo.y = (r2 & 0xffffu) | (r3 << 16);
      hi.x = (r0 >> 16) | (r1 & 0xffff0000u);
      hi.y = (r2 >> 16) | (r3 & 0xffff0000u);
      *(uint2*)&Vt[d * 64 + ((t0 >> 1) ^ (d & 7)) * 8 + (t0 & 1) * 4] = lo;
      const int d1 = d + 1;
      *(uint2*)&Vt[d1 * 64 + ((t0 >> 1) ^ (d1 & 7)) * 8 + (t0 & 1) * 4] = hi;
    }
    if (tc < 3) {
      #pragma unroll
      for (int i = 0; i < 2; i++) {
        const int u = i * 256 + tid;
        const int t0 = u >> 5, d = (u & 31) * 2;
        #pragma unroll
        for (int k = 0; k < 4; k++)
          vr[i][k] = *(const unsigned int*)(vbase + (size_t)((tc + 1) * 64 + t0 + 16 * k) * 3072 + d);
      }
    }

    #pragma unroll
    for (int mt = 0; mt < 4; mt++) {
      f32x4 sacc[4] = {zero4, zero4, zero4, zero4};
      #pragma unroll
      for (int kc = 0; kc < 2; kc++)
        #pragma unroll
        for (int nt = 0; nt < 4; nt++) {
          const bf16x8 kf = *(const bf16x8*)&Kt[(nt * 16 + cl) * 64 + ((kc * 4 + gr) ^ (cl & 7)) * 8];
          sacc[nt] = __builtin_amdgcn_mfma_f32_16x16x32_bf16(qf[mt][kc], kf, sacc[nt], 0, 0, 0);
        }
      #pragma unroll
      for (int r = 0; r < 4; r++) {
        const float p0 = __expf(sacc[0][r] * 0.125f);
        const float p1 = __expf(sacc[1][r] * 0.125f);
        const float p2 = __expf(sacc[2][r] * 0.125f);
        const float p3 = __expf(sacc[3][r] * 0.125f);
        lsum[mt][r] += (p0 + p1) + (p2 + p3);
        float2 f01; f01.x = p0; f01.y = p1;
        float2 f23; f23.x = p2; f23.y = p3;
        __hip_bfloat162 b01 = __float22bfloat162_rn(f01);
        __hip_bfloat162 b23 = __float22bfloat162_rn(f23);
        union { __hip_bfloat162 h; unsigned int u; } c0, c1;
        c0.h = b01; c1.h = b23;
        uint2 w; w.x = c0.u; w.y = c1.u;
        const int m = mt * 16 + gr * 4 + r;
        *(uint2*)&Qp[wid][m * 64 + ((cl >> 1) ^ (m & 7)) * 8 + (cl & 1) * 4] = w;
      }
    }
    __syncthreads();

    if (tc < 3) {
      #pragma unroll
      for (int i = 0; i < 2; i++) {
        const int r0 = (wid * 2 + i) * 8;
        gl_lds16(kbase + (size_t)((tc + 1) * 64 + r0 + l8) * 3072 + (l7 ^ l8) * 8, &Kt[r0 * 64]);
      }
    }

    #pragma unroll
    for (int kc = 0; kc < 2; kc++) {
      bf16x8 vf[4], pf[4];
      #pragma unroll
      for (int dt = 0; dt < 4; dt++)
        vf[dt] = *(const bf16x8*)&Vt[(dt * 16 + cl) * 64 + ((kc * 4 + gr) ^ (cl & 7)) * 8];
      #pragma unroll
      for (int mt = 0; mt < 4; mt++)
        pf[mt] = *(const bf16x8*)&Qp[wid][(mt * 16 + cl) * 64 + ((kc * 4 + gr) ^ (cl & 7)) * 8];
      #pragma unroll
      for (int mt = 0; mt < 4; mt++)
        #pragma unroll
        for (int dt = 0; dt < 4; dt++)
          o[mt][dt] = __builtin_amdgcn_mfma_f32_16x16x32_bf16(pf[mt], vf[dt], o[mt][dt], 0, 0, 0);
    }
    __syncthreads();
  }

  #pragma unroll
  for (int mt = 0; mt < 4; mt++)
    #pragma unroll
    for (int r = 0; r < 4; r++) {
      float l = lsum[mt][r];
      l += __shfl_xor(l, 1);
      l += __shfl_xor(l, 2);
      l += __shfl_xor(l, 4);
      l += __shfl_xor(l, 8);
      const float inv = 1.0f / l;
      const int srow = wid * 64 + mt * 16 + gr * 4 + r;
      #pragma unroll
      for (int dt = 0; dt < 4; dt++)
        attn_out[(size_t)(n * 256 + srow) * 1024 + h * 64 + dt * 16 + cl] =
            f2bf(o[mt][dt][r] * inv);
    }
}

extern "C" void kernel_launch(void* const* d_in, const int* in_sizes, int n_in,
                              void* d_out, int out_size, void* d_ws, size_t ws_size,
                              hipStream_t stream) {
  const float* x      = (const float*)d_in[0];   // (4,32,16,16,1024)
  const float* w_qkv  = (const float*)d_in[1];   // (1024,3072)
  const float* w_proj = (const float*)d_in[2];   // (1024,1024)
  const float* b_proj = (const float*)d_in[3];   // (1024,)
  float* out = (float*)d_out;
  char* ws = (char*)d_ws;

  unsigned short* x_bf    = (unsigned short*)ws;                // 64 MiB (reused as attn out)
  unsigned short* wqkvT   = (unsigned short*)(ws + 67108864);   // [3072][1024]
  unsigned short* wprojT  = (unsigned short*)(ws + 73400320);   // [1024][1024]
  unsigned short* qkvb    = (unsigned short*)(ws + 75497472);   // [32768][3072]
  unsigned short* attn_bf = x_bf;

  k_conv_x<<<32768, 256, 0, stream>>>((const float4*)x, (ushort4_t*)x_bf, 8388608);
  k_transpose_bf16<<<dim3(48, 16), 256, 0, stream>>>(w_qkv, wqkvT, 1024, 3072);
  k_transpose_bf16<<<dim3(16, 16), 256, 0, stream>>>(w_proj, wprojT, 1024, 1024);

  // qkv = x @ w_qkv with fused 2D-RoPE on q,k (M=32768, N=3072, K=1024)
  k_gemm_bt<0, 1><<<dim3(24, 128), 512, 0, stream>>>(x_bf, wqkvT, qkvb, nullptr, nullptr,
                                                     32768, 3072, 1024);
  // flash attention, one block per (n, head)
  k_attn<<<2048, 256, 0, stream>>>(qkvb, attn_bf);

  // out = attn @ w_proj + b_proj (M=32768, N=1024, K=1024)
  k_gemm_bt<1, 0><<<dim3(8, 128), 512, 0, stream>>>(attn_bf, wprojT, nullptr, out, b_proj,
                                                    32768, 1024, 1024);
}

// Round 3
// 657.183 us; speedup vs baseline: 1.1121x; 1.0724x over previous
//
#include <hip/hip_runtime.h>
#include <hip/hip_bf16.h>
#include <stdint.h>

typedef __attribute__((ext_vector_type(8))) short bf16x8;
typedef __attribute__((ext_vector_type(4))) float f32x4;
typedef __attribute__((ext_vector_type(4))) unsigned short ushort4_t;

__device__ __forceinline__ unsigned short f2bf(float f) {
  union { float f; unsigned int i; } x; x.f = f;
  return (unsigned short)((x.i + 0x7fffu + ((x.i >> 16) & 1u)) >> 16);
}

// async global->LDS, 16B per lane; LDS dest is wave-uniform base + lane*16
__device__ __forceinline__ void gl_lds16(const void* g, void* l) {
  __builtin_amdgcn_global_load_lds(
      (const __attribute__((address_space(1))) unsigned int*)(uintptr_t)g,
      (__attribute__((address_space(3))) unsigned int*)(uint32_t)(uintptr_t)l,
      16, 0, 0);
}

// raw barrier (no vmcnt/lgkmcnt drain!) with compiler memory fences so LDS
// reads/writes and global_load_lds issues cannot be moved across it.
__device__ __forceinline__ void bar() {
  asm volatile("" ::: "memory");
  __builtin_amdgcn_s_barrier();
  asm volatile("" ::: "memory");
}

// inv_freq[j] = 10000^(-j/16), j = 0..15 (d_half=32, 16 freqs)
__constant__ float INVF[16] = {
  1.0f,   0.56234132519f,  0.31622776601f,  0.17782794100f,
  0.1f,   0.056234132519f, 0.031622776601f, 0.017782794100f,
  0.01f,  0.0056234132519f,0.0031622776601f,0.0017782794100f,
  0.001f, 0.00056234132519f,0.00031622776601f,0.00017782794100f
};

// ---- fp32 -> bf16 bulk convert (x) ----
__global__ __launch_bounds__(256) void k_conv_x(const float4* __restrict__ src,
                                                ushort4_t* __restrict__ dst, int n4) {
  int i = blockIdx.x * 256 + threadIdx.x;
  if (i < n4) {
    float4 v = src[i];
    ushort4_t r = { f2bf(v.x), f2bf(v.y), f2bf(v.z), f2bf(v.w) };
    dst[i] = r;
  }
}

// ---- fp32 RxC -> bf16 CxR transpose (weights to B^T layout) ----
__global__ __launch_bounds__(256) void k_transpose_bf16(const float* __restrict__ src,
                                                        unsigned short* __restrict__ dst,
                                                        int R, int C) {
  __shared__ unsigned short tile[64][65];
  const int bj = blockIdx.x, bi = blockIdx.y;
  const int t = threadIdx.x, lr = t >> 6, lc = t & 63;
  #pragma unroll
  for (int i = 0; i < 16; i++) {
    int r = i * 4 + lr;
    tile[r][lc] = f2bf(src[(size_t)(bi * 64 + r) * C + bj * 64 + lc]);
  }
  __syncthreads();
  #pragma unroll
  for (int i = 0; i < 16; i++) {
    int r = i * 4 + lr;
    dst[(size_t)(bj * 64 + r) * R + bi * 64 + lc] = tile[lc][r];
  }
}

// ---- Pipelined GEMM: C[M,N] = A[M,K] * B[N,K]^T, bf16 in, bf16 or f32(+bias) out
//
// R3 geometry (m201-class): BM=256, BN=256, BK=64. 512 threads = 8 waves
// (2M x 4N), 128x64 output per wave -> 64 MFMA per 24 ds_read_b128 per K-tile
// (2.67 MFMA/read vs 2.0 at the old 64x64/wave). Per-CU per-tile: MFMA wall
// ~620 cyc vs LDS (192KB read + 64KB staged)/256B-cyc ~1000 cyc -> ~62%
// MfmaUtil ceiling (matches m201's measured 62.1%). LDS: 2 slots x (A 256x64
// + B 256x64) = 128 KB, double-buffered.
//
// Schedule (R2 skeleton, verified): ONE barrier per tile. Stage tile c+1 into
// slot s^1 at the top of tile c (slot s^1's previous reads completed before
// the last barrier -- all 24 fragment reads are consumed by MFMAs before it).
// End of tile: per-wave vmcnt(0) retires tile c+1's 8 loads (issued a full
// tile ~1000cyc earlier -> cheap), then barrier gives cross-wave visibility.
// kc-outer fragment order keeps live regs at acc128+bv32+af32 (~220 VGPR);
// __launch_bounds__(512,2) pins <=256 so 2 waves/SIMD co-schedule (the LDS
// bursts of one wave hide under the other's MFMAs; setprio biases the MFMA
// wave). XOR chunk swizzle (LDS chunk t of row r holds global chunk t^(r&7),
// via pre-swizzled global source) -- conflict-free ds_read_b128, PMC 0.
// ROPE=1: fused 2D-RoPE epilogue on the q/k cols (wave's 64-col group = 1 head).
template<int F32OUT, int ROPE>
__global__ __launch_bounds__(512, 2) void k_gemm_bt(
    const unsigned short* __restrict__ A, const unsigned short* __restrict__ B,
    unsigned short* __restrict__ Cb, float* __restrict__ Cf,
    const float* __restrict__ bias, int M, int N, int K) {
  __shared__ __align__(16) unsigned short As[2 * 256 * 64];  // 64 KB
  __shared__ __align__(16) unsigned short Bs[2 * 256 * 64];  // 64 KB
  const int tid = threadIdx.x;
  const int lane = tid & 63, wid = tid >> 6;
  const int cl = lane & 15, gr = lane >> 4;
  const int wm = wid >> 2, wn = wid & 3;     // 2M x 4N wave grid
  const int l8 = lane >> 3, l7 = lane & 7;
  const int mBase = blockIdx.y * 256, nBase = blockIdx.x * 256;
  const int KT = K >> 6;                 // 64-wide K chunks (16 here)
  const int ldsW = (wid * 8) * 64;       // wave-uniform LDS row-base offset

  // per-thread global source pointers (include row and pre-swizzled chunk)
  const unsigned short* aP[4];
  const unsigned short* bP[4];
  #pragma unroll
  for (int i = 0; i < 4; i++) {
    aP[i] = A + (size_t)(mBase + i * 64 + wid * 8 + l8) * K + (l7 ^ l8) * 8;
    bP[i] = B + (size_t)(nBase + i * 64 + wid * 8 + l8) * K + (l7 ^ l8) * 8;
  }

  const f32x4 zero4 = {0.f, 0.f, 0.f, 0.f};
  f32x4 acc[8][4];
  #pragma unroll
  for (int a = 0; a < 8; a++)
    #pragma unroll
    for (int b = 0; b < 4; b++) acc[a][b] = zero4;

  // prologue: tile 0 -> slot 0, tile 1 -> slot 1 (8 loads each, in order)
  #pragma unroll
  for (int i = 0; i < 4; i++) gl_lds16(aP[i], &As[(i * 64) * 64 + ldsW]);
  #pragma unroll
  for (int i = 0; i < 4; i++) gl_lds16(bP[i], &Bs[(i * 64) * 64 + ldsW]);
  #pragma unroll
  for (int i = 0; i < 4; i++) gl_lds16(aP[i] + 64, &As[16384 + (i * 64) * 64 + ldsW]);
  #pragma unroll
  for (int i = 0; i < 4; i++) gl_lds16(bP[i] + 64, &Bs[16384 + (i * 64) * 64 + ldsW]);
  asm volatile("s_waitcnt vmcnt(8)" ::: "memory");  // tile 0 landed, tile 1 in flight
  bar();

  for (int c = 0; c < KT; ++c) {
    const int s = c & 1;
    const unsigned short* as_ = As + s * 16384;
    const unsigned short* bs_ = Bs + s * 16384;

    // stage tile c+1 into the other slot (its old reads done before last barrier)
    if (c + 1 < KT) {
      const int koff = (c + 1) * 64;
      const int so = (s ^ 1) * 16384;
      #pragma unroll
      for (int i = 0; i < 4; i++) gl_lds16(aP[i] + koff, &As[so + (i * 64) * 64 + ldsW]);
      #pragma unroll
      for (int i = 0; i < 4; i++) gl_lds16(bP[i] + koff, &Bs[so + (i * 64) * 64 + ldsW]);
    }

    #pragma unroll
    for (int kc = 0; kc < 2; ++kc) {
      const int coff = ((kc * 4 + gr) ^ (cl & 7)) * 8;
      bf16x8 bv[4];
      #pragma unroll
      for (int nt = 0; nt < 4; nt++)
        bv[nt] = *(const bf16x8*)&bs_[(wn * 64 + nt * 16 + cl) * 64 + coff];
      #pragma unroll
      for (int h = 0; h < 2; ++h) {
        bf16x8 af[4];
        #pragma unroll
        for (int t = 0; t < 4; t++)
          af[t] = *(const bf16x8*)&as_[(wm * 128 + h * 64 + t * 16 + cl) * 64 + coff];
        __builtin_amdgcn_s_setprio(1);
        #pragma unroll
        for (int mt = 0; mt < 4; mt++)
          #pragma unroll
          for (int nt = 0; nt < 4; nt++)
            acc[h * 4 + mt][nt] =
                __builtin_amdgcn_mfma_f32_16x16x32_bf16(af[mt], bv[nt], acc[h * 4 + mt][nt], 0, 0, 0);
        __builtin_amdgcn_s_setprio(0);
      }
    }

    // end of tile: this wave's next-tile loads retired, then cross-wave barrier
    if (c + 1 < KT) {
      asm volatile("s_waitcnt vmcnt(0)" ::: "memory");
      bar();
    }
  }

  if (ROPE && nBase < 2048) {  // q or k region of qkv output (wave-uniform)
    const float f = INVF[cl];
    #pragma unroll
    for (int amt = 0; amt < 8; amt++)
      #pragma unroll
      for (int r = 0; r < 4; r++) {
        const int sp = (mBase + wm * 128 + amt * 16 + gr * 4 + r) & 255;
        float sh, ch, sw, cw;
        __sincosf((float)(sp >> 4) * f, &sh, &ch);
        __sincosf((float)(sp & 15) * f, &sw, &cw);
        const float a = acc[amt][0][r], b = acc[amt][1][r];
        const float cc = acc[amt][2][r], d = acc[amt][3][r];
        acc[amt][0][r] = a * ch - b * sh;
        acc[amt][1][r] = b * ch + a * sh;
        acc[amt][2][r] = cc * cw - d * sw;
        acc[amt][3][r] = d * cw + cc * sw;
      }
  }

  // C/D layout (m89-verified): col = lane&15, row = (lane>>4)*4 + reg
  #pragma unroll
  for (int amt = 0; amt < 8; amt++)
    #pragma unroll
    for (int nt = 0; nt < 4; nt++)
      #pragma unroll
      for (int r = 0; r < 4; r++) {
        const int row = mBase + wm * 128 + amt * 16 + gr * 4 + r;
        const int col = nBase + wn * 64 + nt * 16 + cl;
        const float v = acc[amt][nt][r];
        if (F32OUT) Cf[(size_t)row * N + col] = v + bias[col];
        else        Cb[(size_t)row * N + col] = f2bf(v);
      }
}

// ---- flash attention (RoPE pre-applied): one block per (n, head); 4 waves x 64 q
// (unchanged this round -- GEMM geometry is the experiment)
__global__ __launch_bounds__(256, 3) void k_attn(const unsigned short* __restrict__ qkv,
                                                 unsigned short* __restrict__ attn_out) {
  __shared__ __align__(16) unsigned short Qp[4][64 * 64];  // per-wave Q, then P
  __shared__ __align__(16) unsigned short Kt[64 * 64];
  __shared__ __align__(16) unsigned short Vt[64 * 64];     // V^T, pi-permuted cols
  const int blk = blockIdx.x;
  const int n = blk >> 4, h = blk & 15;
  const int tid = threadIdx.x;
  const int lane = tid & 63, wid = tid >> 6;
  const int cl = lane & 15, gr = lane >> 4;
  const int l8 = lane >> 3, l7 = lane & 7;
  const unsigned short* qbase = qkv + (size_t)n * 256 * 3072 + h * 64;
  const unsigned short* kbase = qbase + 1024;
  const unsigned short* vbase = qbase + 2048;

  #pragma unroll
  for (int i = 0; i < 8; i++)
    gl_lds16(qbase + (size_t)(wid * 64 + i * 8 + l8) * 3072 + (l7 ^ l8) * 8,
             &Qp[wid][i * 8 * 64]);
  #pragma unroll
  for (int i = 0; i < 2; i++) {
    const int r0 = (wid * 2 + i) * 8;
    gl_lds16(kbase + (size_t)(r0 + l8) * 3072 + (l7 ^ l8) * 8, &Kt[r0 * 64]);
  }

  unsigned int vr[2][4];
  #pragma unroll
  for (int i = 0; i < 2; i++) {
    const int u = i * 256 + tid;
    const int t0 = u >> 5, d = (u & 31) * 2;
    #pragma unroll
    for (int k = 0; k < 4; k++)
      vr[i][k] = *(const unsigned int*)(vbase + (size_t)(t0 + 16 * k) * 3072 + d);
  }
  __syncthreads();

  bf16x8 qf[4][2];
  #pragma unroll
  for (int mt = 0; mt < 4; mt++)
    #pragma unroll
    for (int kc = 0; kc < 2; kc++)
      qf[mt][kc] = *(const bf16x8*)&Qp[wid][(mt * 16 + cl) * 64 + ((kc * 4 + gr) ^ (cl & 7)) * 8];

  const f32x4 zero4 = {0.f, 0.f, 0.f, 0.f};
  f32x4 o[4][4];
  float lsum[4][4];
  #pragma unroll
  for (int a = 0; a < 4; a++)
    #pragma unroll
    for (int b = 0; b < 4; b++) { o[a][b] = zero4; lsum[a][b] = 0.f; }

  for (int tc = 0; tc < 4; tc++) {
    #pragma unroll
    for (int i = 0; i < 2; i++) {
      const int u = i * 256 + tid;
      const int t0 = u >> 5, d = (u & 31) * 2;
      const unsigned int r0 = vr[i][0], r1 = vr[i][1], r2 = vr[i][2], r3 = vr[i][3];
      uint2 lo, hi;
      lo.x = (r0 & 0xffffu) | (r1 << 16);
      lo.y = (r2 & 0xffffu) | (r3 << 16);
      hi.x = (r0 >> 16) | (r1 & 0xffff0000u);
      hi.y = (r2 >> 16) | (r3 & 0xffff0000u);
      *(uint2*)&Vt[d * 64 + ((t0 >> 1) ^ (d & 7)) * 8 + (t0 & 1) * 4] = lo;
      const int d1 = d + 1;
      *(uint2*)&Vt[d1 * 64 + ((t0 >> 1) ^ (d1 & 7)) * 8 + (t0 & 1) * 4] = hi;
    }
    if (tc < 3) {
      #pragma unroll
      for (int i = 0; i < 2; i++) {
        const int u = i * 256 + tid;
        const int t0 = u >> 5, d = (u & 31) * 2;
        #pragma unroll
        for (int k = 0; k < 4; k++)
          vr[i][k] = *(const unsigned int*)(vbase + (size_t)((tc + 1) * 64 + t0 + 16 * k) * 3072 + d);
      }
    }

    #pragma unroll
    for (int mt = 0; mt < 4; mt++) {
      f32x4 sacc[4] = {zero4, zero4, zero4, zero4};
      #pragma unroll
      for (int kc = 0; kc < 2; kc++)
        #pragma unroll
        for (int nt = 0; nt < 4; nt++) {
          const bf16x8 kf = *(const bf16x8*)&Kt[(nt * 16 + cl) * 64 + ((kc * 4 + gr) ^ (cl & 7)) * 8];
          sacc[nt] = __builtin_amdgcn_mfma_f32_16x16x32_bf16(qf[mt][kc], kf, sacc[nt], 0, 0, 0);
        }
      #pragma unroll
      for (int r = 0; r < 4; r++) {
        const float p0 = __expf(sacc[0][r] * 0.125f);
        const float p1 = __expf(sacc[1][r] * 0.125f);
        const float p2 = __expf(sacc[2][r] * 0.125f);
        const float p3 = __expf(sacc[3][r] * 0.125f);
        lsum[mt][r] += (p0 + p1) + (p2 + p3);
        float2 f01; f01.x = p0; f01.y = p1;
        float2 f23; f23.x = p2; f23.y = p3;
        __hip_bfloat162 b01 = __float22bfloat162_rn(f01);
        __hip_bfloat162 b23 = __float22bfloat162_rn(f23);
        union { __hip_bfloat162 h; unsigned int u; } c0, c1;
        c0.h = b01; c1.h = b23;
        uint2 w; w.x = c0.u; w.y = c1.u;
        const int m = mt * 16 + gr * 4 + r;
        *(uint2*)&Qp[wid][m * 64 + ((cl >> 1) ^ (m & 7)) * 8 + (cl & 1) * 4] = w;
      }
    }
    __syncthreads();

    if (tc < 3) {
      #pragma unroll
      for (int i = 0; i < 2; i++) {
        const int r0 = (wid * 2 + i) * 8;
        gl_lds16(kbase + (size_t)((tc + 1) * 64 + r0 + l8) * 3072 + (l7 ^ l8) * 8, &Kt[r0 * 64]);
      }
    }

    #pragma unroll
    for (int kc = 0; kc < 2; kc++) {
      bf16x8 vf[4], pf[4];
      #pragma unroll
      for (int dt = 0; dt < 4; dt++)
        vf[dt] = *(const bf16x8*)&Vt[(dt * 16 + cl) * 64 + ((kc * 4 + gr) ^ (cl & 7)) * 8];
      #pragma unroll
      for (int mt = 0; mt < 4; mt++)
        pf[mt] = *(const bf16x8*)&Qp[wid][(mt * 16 + cl) * 64 + ((kc * 4 + gr) ^ (cl & 7)) * 8];
      #pragma unroll
      for (int mt = 0; mt < 4; mt++)
        #pragma unroll
        for (int dt = 0; dt < 4; dt++)
          o[mt][dt] = __builtin_amdgcn_mfma_f32_16x16x32_bf16(pf[mt], vf[dt], o[mt][dt], 0, 0, 0);
    }
    __syncthreads();
  }

  #pragma unroll
  for (int mt = 0; mt < 4; mt++)
    #pragma unroll
    for (int r = 0; r < 4; r++) {
      float l = lsum[mt][r];
      l += __shfl_xor(l, 1);
      l += __shfl_xor(l, 2);
      l += __shfl_xor(l, 4);
      l += __shfl_xor(l, 8);
      const float inv = 1.0f / l;
      const int srow = wid * 64 + mt * 16 + gr * 4 + r;
      #pragma unroll
      for (int dt = 0; dt < 4; dt++)
        attn_out[(size_t)(n * 256 + srow) * 1024 + h * 64 + dt * 16 + cl] =
            f2bf(o[mt][dt][r] * inv);
    }
}

extern "C" void kernel_launch(void* const* d_in, const int* in_sizes, int n_in,
                              void* d_out, int out_size, void* d_ws, size_t ws_size,
                              hipStream_t stream) {
  const float* x      = (const float*)d_in[0];   // (4,32,16,16,1024)
  const float* w_qkv  = (const float*)d_in[1];   // (1024,3072)
  const float* w_proj = (const float*)d_in[2];   // (1024,1024)
  const float* b_proj = (const float*)d_in[3];   // (1024,)
  float* out = (float*)d_out;
  char* ws = (char*)d_ws;

  unsigned short* x_bf    = (unsigned short*)ws;                // 64 MiB (reused as attn out)
  unsigned short* wqkvT   = (unsigned short*)(ws + 67108864);   // [3072][1024]
  unsigned short* wprojT  = (unsigned short*)(ws + 73400320);   // [1024][1024]
  unsigned short* qkvb    = (unsigned short*)(ws + 75497472);   // [32768][3072]
  unsigned short* attn_bf = x_bf;

  k_conv_x<<<32768, 256, 0, stream>>>((const float4*)x, (ushort4_t*)x_bf, 8388608);
  k_transpose_bf16<<<dim3(48, 16), 256, 0, stream>>>(w_qkv, wqkvT, 1024, 3072);
  k_transpose_bf16<<<dim3(16, 16), 256, 0, stream>>>(w_proj, wprojT, 1024, 1024);

  // qkv = x @ w_qkv with fused 2D-RoPE on q,k (M=32768, N=3072, K=1024)
  k_gemm_bt<0, 1><<<dim3(12, 128), 512, 0, stream>>>(x_bf, wqkvT, qkvb, nullptr, nullptr,
                                                     32768, 3072, 1024);
  // flash attention, one block per (n, head)
  k_attn<<<2048, 256, 0, stream>>>(qkvb, attn_bf);

  // out = attn @ w_proj + b_proj (M=32768, N=1024, K=1024)
  k_gemm_bt<1, 0><<<dim3(4, 128), 512, 0, stream>>>(attn_bf, wprojT, nullptr, out, b_proj,
                                                    32768, 1024, 1024);
}

// Round 4
// 645.887 us; speedup vs baseline: 1.1316x; 1.0175x over previous
//
#include <hip/hip_runtime.h>
#include <hip/hip_bf16.h>
#include <stdint.h>

typedef __attribute__((ext_vector_type(8))) short bf16x8;
typedef __attribute__((ext_vector_type(4))) float f32x4;
typedef __attribute__((ext_vector_type(4))) unsigned short ushort4_t;

__device__ __forceinline__ unsigned short f2bf(float f) {
  union { float f; unsigned int i; } x; x.f = f;
  return (unsigned short)((x.i + 0x7fffu + ((x.i >> 16) & 1u)) >> 16);
}

// async global->LDS, 16B per lane; LDS dest is wave-uniform base + lane*16
__device__ __forceinline__ void gl_lds16(const void* g, void* l) {
  __builtin_amdgcn_global_load_lds(
      (const __attribute__((address_space(1))) unsigned int*)(uintptr_t)g,
      (__attribute__((address_space(3))) unsigned int*)(uint32_t)(uintptr_t)l,
      16, 0, 0);
}

// raw barrier (no vmcnt/lgkmcnt drain!) with compiler memory fences so LDS
// reads/writes and global_load_lds issues cannot be moved across it.
__device__ __forceinline__ void bar() {
  asm volatile("" ::: "memory");
  __builtin_amdgcn_s_barrier();
  asm volatile("" ::: "memory");
}

// inv_freq[j] = 10000^(-j/16), j = 0..15 (d_half=32, 16 freqs)
__constant__ float INVF[16] = {
  1.0f,   0.56234132519f,  0.31622776601f,  0.17782794100f,
  0.1f,   0.056234132519f, 0.031622776601f, 0.017782794100f,
  0.01f,  0.0056234132519f,0.0031622776601f,0.0017782794100f,
  0.001f, 0.00056234132519f,0.00031622776601f,0.00017782794100f
};

// ---- fp32 -> bf16 bulk convert (x) ----
__global__ __launch_bounds__(256) void k_conv_x(const float4* __restrict__ src,
                                                ushort4_t* __restrict__ dst, int n4) {
  int i = blockIdx.x * 256 + threadIdx.x;
  if (i < n4) {
    float4 v = src[i];
    ushort4_t r = { f2bf(v.x), f2bf(v.y), f2bf(v.z), f2bf(v.w) };
    dst[i] = r;
  }
}

// ---- fp32 RxC -> bf16 CxR transpose (weights to B^T layout) ----
__global__ __launch_bounds__(256) void k_transpose_bf16(const float* __restrict__ src,
                                                        unsigned short* __restrict__ dst,
                                                        int R, int C) {
  __shared__ unsigned short tile[64][65];
  const int bj = blockIdx.x, bi = blockIdx.y;
  const int t = threadIdx.x, lr = t >> 6, lc = t & 63;
  #pragma unroll
  for (int i = 0; i < 16; i++) {
    int r = i * 4 + lr;
    tile[r][lc] = f2bf(src[(size_t)(bi * 64 + r) * C + bj * 64 + lc]);
  }
  __syncthreads();
  #pragma unroll
  for (int i = 0; i < 16; i++) {
    int r = i * 4 + lr;
    dst[(size_t)(bj * 64 + r) * R + bi * 64 + lc] = tile[lc][r];
  }
}

// ---- Pipelined GEMM: C[M,N] = A[M,K] * B[N,K]^T, bf16 in, bf16 or f32(+bias) out
//
// Geometry (m201-class): BM=256, BN=256, BK=64. 512 threads = 8 waves
// (2M x 4N), 128x64 output per wave. LDS: 2 slots x (A+B 256x64) = 128 KB.
//
// R4: walls per K-tile per CU are BALANCED (MFMA 512x4.85~2480 cyc; LDS
// 192 ds_read_b128 x12 + staged writes ~2560 cyc) -- R3 measured 5487
// cyc/tile = fully SERIALIZED because setprio fences around each MFMA
// cluster blocked the compiler from hoisting the next cluster's ds_reads.
// Fix: issue ALL 24 fragment reads up front (bv0,af00,af01,bv1,af10,af11),
// ONE setprio pair around all 4 MFMA clusters. Compiler emits descending
// counted lgkmcnt between clusters (m97-verified), so the later 16 reads
// drain through the LDS pipe UNDER the earlier MFMA clusters.
// Schedule otherwise: ONE barrier per tile; stage tile c+1 at tile top;
// per-wave vmcnt(0) (loads issued a full tile earlier -> cheap) + barrier.
// XCD swizzle (bijective, nwg%8==0): each XCD owns a contiguous run of
// flat tile indices -> the 12 blocks sharing an A-panel hit the same L2.
// XOR chunk swizzle -- conflict-free ds_read_b128, PMC 0.
// ROPE=1: fused 2D-RoPE epilogue on the q/k cols (wave's 64-col group = 1 head).
template<int F32OUT, int ROPE>
__global__ __launch_bounds__(512, 2) void k_gemm_bt(
    const unsigned short* __restrict__ A, const unsigned short* __restrict__ B,
    unsigned short* __restrict__ Cb, float* __restrict__ Cf,
    const float* __restrict__ bias, int M, int N, int K) {
  __shared__ __align__(16) unsigned short As[2 * 256 * 64];  // 64 KB
  __shared__ __align__(16) unsigned short Bs[2 * 256 * 64];  // 64 KB
  const int tid = threadIdx.x;
  const int lane = tid & 63, wid = tid >> 6;
  const int cl = lane & 15, gr = lane >> 4;
  const int wm = wid >> 2, wn = wid & 3;     // 2M x 4N wave grid
  const int l8 = lane >> 3, l7 = lane & 7;

  // XCD-aware bijective block swizzle (requires nwg % 8 == 0; holds here)
  const int gx = gridDim.x;
  const int nwg = gx * gridDim.y;
  const int f = blockIdx.y * gx + blockIdx.x;
  const int q = nwg >> 3;
  const int nid = (f & 7) * q + (f >> 3);
  const int bx = nid % gx, by = nid / gx;
  const int mBase = by * 256, nBase = bx * 256;

  const int KT = K >> 6;                 // 64-wide K chunks (16 here)
  const int ldsW = (wid * 8) * 64;       // wave-uniform LDS row-base offset

  // per-thread global source pointers (include row and pre-swizzled chunk)
  const unsigned short* aP[4];
  const unsigned short* bP[4];
  #pragma unroll
  for (int i = 0; i < 4; i++) {
    aP[i] = A + (size_t)(mBase + i * 64 + wid * 8 + l8) * K + (l7 ^ l8) * 8;
    bP[i] = B + (size_t)(nBase + i * 64 + wid * 8 + l8) * K + (l7 ^ l8) * 8;
  }

  const f32x4 zero4 = {0.f, 0.f, 0.f, 0.f};
  f32x4 acc[8][4];
  #pragma unroll
  for (int a = 0; a < 8; a++)
    #pragma unroll
    for (int b = 0; b < 4; b++) acc[a][b] = zero4;

  // prologue: tile 0 -> slot 0, tile 1 -> slot 1 (8 loads each, in order)
  #pragma unroll
  for (int i = 0; i < 4; i++) gl_lds16(aP[i], &As[(i * 64) * 64 + ldsW]);
  #pragma unroll
  for (int i = 0; i < 4; i++) gl_lds16(bP[i], &Bs[(i * 64) * 64 + ldsW]);
  #pragma unroll
  for (int i = 0; i < 4; i++) gl_lds16(aP[i] + 64, &As[16384 + (i * 64) * 64 + ldsW]);
  #pragma unroll
  for (int i = 0; i < 4; i++) gl_lds16(bP[i] + 64, &Bs[16384 + (i * 64) * 64 + ldsW]);
  asm volatile("s_waitcnt vmcnt(8)" ::: "memory");  // tile 0 landed, tile 1 in flight
  bar();

  for (int c = 0; c < KT; ++c) {
    const int s = c & 1;
    const unsigned short* as_ = As + s * 16384;
    const unsigned short* bs_ = Bs + s * 16384;

    // stage tile c+1 into the other slot (its old reads done before last barrier)
    if (c + 1 < KT) {
      const int koff = (c + 1) * 64;
      const int so = (s ^ 1) * 16384;
      #pragma unroll
      for (int i = 0; i < 4; i++) gl_lds16(aP[i] + koff, &As[so + (i * 64) * 64 + ldsW]);
      #pragma unroll
      for (int i = 0; i < 4; i++) gl_lds16(bP[i] + koff, &Bs[so + (i * 64) * 64 + ldsW]);
    }

    // ALL 24 fragment reads issued up front, in consumption order.
    const int c0 = ((0 * 4 + gr) ^ (cl & 7)) * 8;
    const int c1 = ((1 * 4 + gr) ^ (cl & 7)) * 8;
    bf16x8 bv0[4], bv1[4], af00[4], af01[4], af10[4], af11[4];
    #pragma unroll
    for (int nt = 0; nt < 4; nt++)
      bv0[nt] = *(const bf16x8*)&bs_[(wn * 64 + nt * 16 + cl) * 64 + c0];
    #pragma unroll
    for (int t = 0; t < 4; t++)
      af00[t] = *(const bf16x8*)&as_[(wm * 128 + 0 * 64 + t * 16 + cl) * 64 + c0];
    #pragma unroll
    for (int t = 0; t < 4; t++)
      af01[t] = *(const bf16x8*)&as_[(wm * 128 + 1 * 64 + t * 16 + cl) * 64 + c0];
    #pragma unroll
    for (int nt = 0; nt < 4; nt++)
      bv1[nt] = *(const bf16x8*)&bs_[(wn * 64 + nt * 16 + cl) * 64 + c1];
    #pragma unroll
    for (int t = 0; t < 4; t++)
      af10[t] = *(const bf16x8*)&as_[(wm * 128 + 0 * 64 + t * 16 + cl) * 64 + c1];
    #pragma unroll
    for (int t = 0; t < 4; t++)
      af11[t] = *(const bf16x8*)&as_[(wm * 128 + 1 * 64 + t * 16 + cl) * 64 + c1];

    // 4 MFMA clusters; compiler inserts counted lgkmcnt between them so the
    // tail reads flow under the head clusters. Same accumulation order as R3.
    __builtin_amdgcn_s_setprio(1);
    #pragma unroll
    for (int mt = 0; mt < 4; mt++)
      #pragma unroll
      for (int nt = 0; nt < 4; nt++)
        acc[0 + mt][nt] = __builtin_amdgcn_mfma_f32_16x16x32_bf16(af00[mt], bv0[nt], acc[0 + mt][nt], 0, 0, 0);
    #pragma unroll
    for (int mt = 0; mt < 4; mt++)
      #pragma unroll
      for (int nt = 0; nt < 4; nt++)
        acc[4 + mt][nt] = __builtin_amdgcn_mfma_f32_16x16x32_bf16(af01[mt], bv0[nt], acc[4 + mt][nt], 0, 0, 0);
    #pragma unroll
    for (int mt = 0; mt < 4; mt++)
      #pragma unroll
      for (int nt = 0; nt < 4; nt++)
        acc[0 + mt][nt] = __builtin_amdgcn_mfma_f32_16x16x32_bf16(af10[mt], bv1[nt], acc[0 + mt][nt], 0, 0, 0);
    #pragma unroll
    for (int mt = 0; mt < 4; mt++)
      #pragma unroll
      for (int nt = 0; nt < 4; nt++)
        acc[4 + mt][nt] = __builtin_amdgcn_mfma_f32_16x16x32_bf16(af11[mt], bv1[nt], acc[4 + mt][nt], 0, 0, 0);
    __builtin_amdgcn_s_setprio(0);

    // end of tile: this wave's next-tile loads retired, then cross-wave barrier
    if (c + 1 < KT) {
      asm volatile("s_waitcnt vmcnt(0)" ::: "memory");
      bar();
    }
  }

  if (ROPE && nBase < 2048) {  // q or k region of qkv output (wave-uniform)
    const float f2 = INVF[cl];
    #pragma unroll
    for (int amt = 0; amt < 8; amt++)
      #pragma unroll
      for (int r = 0; r < 4; r++) {
        const int sp = (mBase + wm * 128 + amt * 16 + gr * 4 + r) & 255;
        float sh, ch, sw, cw;
        __sincosf((float)(sp >> 4) * f2, &sh, &ch);
        __sincosf((float)(sp & 15) * f2, &sw, &cw);
        const float a = acc[amt][0][r], b = acc[amt][1][r];
        const float cc = acc[amt][2][r], d = acc[amt][3][r];
        acc[amt][0][r] = a * ch - b * sh;
        acc[amt][1][r] = b * ch + a * sh;
        acc[amt][2][r] = cc * cw - d * sw;
        acc[amt][3][r] = d * cw + cc * sw;
      }
  }

  // C/D layout (m89-verified): col = lane&15, row = (lane>>4)*4 + reg
  #pragma unroll
  for (int amt = 0; amt < 8; amt++)
    #pragma unroll
    for (int nt = 0; nt < 4; nt++)
      #pragma unroll
      for (int r = 0; r < 4; r++) {
        const int row = mBase + wm * 128 + amt * 16 + gr * 4 + r;
        const int col = nBase + wn * 64 + nt * 16 + cl;
        const float v = acc[amt][nt][r];
        if (F32OUT) Cf[(size_t)row * N + col] = v + bias[col];
        else        Cb[(size_t)row * N + col] = f2bf(v);
      }
}

// ---- flash attention (RoPE pre-applied): one block per (n, head); 4 waves x 64 q
// (unchanged this round -- GEMM schedule is the experiment)
__global__ __launch_bounds__(256, 3) void k_attn(const unsigned short* __restrict__ qkv,
                                                 unsigned short* __restrict__ attn_out) {
  __shared__ __align__(16) unsigned short Qp[4][64 * 64];  // per-wave Q, then P
  __shared__ __align__(16) unsigned short Kt[64 * 64];
  __shared__ __align__(16) unsigned short Vt[64 * 64];     // V^T, pi-permuted cols
  const int blk = blockIdx.x;
  const int n = blk >> 4, h = blk & 15;
  const int tid = threadIdx.x;
  const int lane = tid & 63, wid = tid >> 6;
  const int cl = lane & 15, gr = lane >> 4;
  const int l8 = lane >> 3, l7 = lane & 7;
  const unsigned short* qbase = qkv + (size_t)n * 256 * 3072 + h * 64;
  const unsigned short* kbase = qbase + 1024;
  const unsigned short* vbase = qbase + 2048;

  #pragma unroll
  for (int i = 0; i < 8; i++)
    gl_lds16(qbase + (size_t)(wid * 64 + i * 8 + l8) * 3072 + (l7 ^ l8) * 8,
             &Qp[wid][i * 8 * 64]);
  #pragma unroll
  for (int i = 0; i < 2; i++) {
    const int r0 = (wid * 2 + i) * 8;
    gl_lds16(kbase + (size_t)(r0 + l8) * 3072 + (l7 ^ l8) * 8, &Kt[r0 * 64]);
  }

  unsigned int vr[2][4];
  #pragma unroll
  for (int i = 0; i < 2; i++) {
    const int u = i * 256 + tid;
    const int t0 = u >> 5, d = (u & 31) * 2;
    #pragma unroll
    for (int k = 0; k < 4; k++)
      vr[i][k] = *(const unsigned int*)(vbase + (size_t)(t0 + 16 * k) * 3072 + d);
  }
  __syncthreads();

  bf16x8 qf[4][2];
  #pragma unroll
  for (int mt = 0; mt < 4; mt++)
    #pragma unroll
    for (int kc = 0; kc < 2; kc++)
      qf[mt][kc] = *(const bf16x8*)&Qp[wid][(mt * 16 + cl) * 64 + ((kc * 4 + gr) ^ (cl & 7)) * 8];

  const f32x4 zero4 = {0.f, 0.f, 0.f, 0.f};
  f32x4 o[4][4];
  float lsum[4][4];
  #pragma unroll
  for (int a = 0; a < 4; a++)
    #pragma unroll
    for (int b = 0; b < 4; b++) { o[a][b] = zero4; lsum[a][b] = 0.f; }

  for (int tc = 0; tc < 4; tc++) {
    #pragma unroll
    for (int i = 0; i < 2; i++) {
      const int u = i * 256 + tid;
      const int t0 = u >> 5, d = (u & 31) * 2;
      const unsigned int r0 = vr[i][0], r1 = vr[i][1], r2 = vr[i][2], r3 = vr[i][3];
      uint2 lo, hi;
      lo.x = (r0 & 0xffffu) | (r1 << 16);
      lo.y = (r2 & 0xffffu) | (r3 << 16);
      hi.x = (r0 >> 16) | (r1 & 0xffff0000u);
      hi.y = (r2 >> 16) | (r3 & 0xffff0000u);
      *(uint2*)&Vt[d * 64 + ((t0 >> 1) ^ (d & 7)) * 8 + (t0 & 1) * 4] = lo;
      const int d1 = d + 1;
      *(uint2*)&Vt[d1 * 64 + ((t0 >> 1) ^ (d1 & 7)) * 8 + (t0 & 1) * 4] = hi;
    }
    if (tc < 3) {
      #pragma unroll
      for (int i = 0; i < 2; i++) {
        const int u = i * 256 + tid;
        const int t0 = u >> 5, d = (u & 31) * 2;
        #pragma unroll
        for (int k = 0; k < 4; k++)
          vr[i][k] = *(const unsigned int*)(vbase + (size_t)((tc + 1) * 64 + t0 + 16 * k) * 3072 + d);
      }
    }

    #pragma unroll
    for (int mt = 0; mt < 4; mt++) {
      f32x4 sacc[4] = {zero4, zero4, zero4, zero4};
      #pragma unroll
      for (int kc = 0; kc < 2; kc++)
        #pragma unroll
        for (int nt = 0; nt < 4; nt++) {
          const bf16x8 kf = *(const bf16x8*)&Kt[(nt * 16 + cl) * 64 + ((kc * 4 + gr) ^ (cl & 7)) * 8];
          sacc[nt] = __builtin_amdgcn_mfma_f32_16x16x32_bf16(qf[mt][kc], kf, sacc[nt], 0, 0, 0);
        }
      #pragma unroll
      for (int r = 0; r < 4; r++) {
        const float p0 = __expf(sacc[0][r] * 0.125f);
        const float p1 = __expf(sacc[1][r] * 0.125f);
        const float p2 = __expf(sacc[2][r] * 0.125f);
        const float p3 = __expf(sacc[3][r] * 0.125f);
        lsum[mt][r] += (p0 + p1) + (p2 + p3);
        float2 f01; f01.x = p0; f01.y = p1;
        float2 f23; f23.x = p2; f23.y = p3;
        __hip_bfloat162 b01 = __float22bfloat162_rn(f01);
        __hip_bfloat162 b23 = __float22bfloat162_rn(f23);
        union { __hip_bfloat162 h; unsigned int u; } c0, c1;
        c0.h = b01; c1.h = b23;
        uint2 w; w.x = c0.u; w.y = c1.u;
        const int m = mt * 16 + gr * 4 + r;
        *(uint2*)&Qp[wid][m * 64 + ((cl >> 1) ^ (m & 7)) * 8 + (cl & 1) * 4] = w;
      }
    }
    __syncthreads();

    if (tc < 3) {
      #pragma unroll
      for (int i = 0; i < 2; i++) {
        const int r0 = (wid * 2 + i) * 8;
        gl_lds16(kbase + (size_t)((tc + 1) * 64 + r0 + l8) * 3072 + (l7 ^ l8) * 8, &Kt[r0 * 64]);
      }
    }

    #pragma unroll
    for (int kc = 0; kc < 2; kc++) {
      bf16x8 vf[4], pf[4];
      #pragma unroll
      for (int dt = 0; dt < 4; dt++)
        vf[dt] = *(const bf16x8*)&Vt[(dt * 16 + cl) * 64 + ((kc * 4 + gr) ^ (cl & 7)) * 8];
      #pragma unroll
      for (int mt = 0; mt < 4; mt++)
        pf[mt] = *(const bf16x8*)&Qp[wid][(mt * 16 + cl) * 64 + ((kc * 4 + gr) ^ (cl & 7)) * 8];
      #pragma unroll
      for (int mt = 0; mt < 4; mt++)
        #pragma unroll
        for (int dt = 0; dt < 4; dt++)
          o[mt][dt] = __builtin_amdgcn_mfma_f32_16x16x32_bf16(pf[mt], vf[dt], o[mt][dt], 0, 0, 0);
    }
    __syncthreads();
  }

  #pragma unroll
  for (int mt = 0; mt < 4; mt++)
    #pragma unroll
    for (int r = 0; r < 4; r++) {
      float l = lsum[mt][r];
      l += __shfl_xor(l, 1);
      l += __shfl_xor(l, 2);
      l += __shfl_xor(l, 4);
      l += __shfl_xor(l, 8);
      const float inv = 1.0f / l;
      const int srow = wid * 64 + mt * 16 + gr * 4 + r;
      #pragma unroll
      for (int dt = 0; dt < 4; dt++)
        attn_out[(size_t)(n * 256 + srow) * 1024 + h * 64 + dt * 16 + cl] =
            f2bf(o[mt][dt][r] * inv);
    }
}

extern "C" void kernel_launch(void* const* d_in, const int* in_sizes, int n_in,
                              void* d_out, int out_size, void* d_ws, size_t ws_size,
                              hipStream_t stream) {
  const float* x      = (const float*)d_in[0];   // (4,32,16,16,1024)
  const float* w_qkv  = (const float*)d_in[1];   // (1024,3072)
  const float* w_proj = (const float*)d_in[2];   // (1024,1024)
  const float* b_proj = (const float*)d_in[3];   // (1024,)
  float* out = (float*)d_out;
  char* ws = (char*)d_ws;

  unsigned short* x_bf    = (unsigned short*)ws;                // 64 MiB (reused as attn out)
  unsigned short* wqkvT   = (unsigned short*)(ws + 67108864);   // [3072][1024]
  unsigned short* wprojT  = (unsigned short*)(ws + 73400320);   // [1024][1024]
  unsigned short* qkvb    = (unsigned short*)(ws + 75497472);   // [32768][3072]
  unsigned short* attn_bf = x_bf;

  k_conv_x<<<32768, 256, 0, stream>>>((const float4*)x, (ushort4_t*)x_bf, 8388608);
  k_transpose_bf16<<<dim3(48, 16), 256, 0, stream>>>(w_qkv, wqkvT, 1024, 3072);
  k_transpose_bf16<<<dim3(16, 16), 256, 0, stream>>>(w_proj, wprojT, 1024, 1024);

  // qkv = x @ w_qkv with fused 2D-RoPE on q,k (M=32768, N=3072, K=1024)
  k_gemm_bt<0, 1><<<dim3(12, 128), 512, 0, stream>>>(x_bf, wqkvT, qkvb, nullptr, nullptr,
                                                     32768, 3072, 1024);
  // flash attention, one block per (n, head)
  k_attn<<<2048, 256, 0, stream>>>(qkvb, attn_bf);

  // out = attn @ w_proj + b_proj (M=32768, N=1024, K=1024)
  k_gemm_bt<1, 0><<<dim3(4, 128), 512, 0, stream>>>(attn_bf, wprojT, nullptr, out, b_proj,
                                                    32768, 1024, 1024);
}

// Round 5
// 640.799 us; speedup vs baseline: 1.1405x; 1.0079x over previous
//
#include <hip/hip_runtime.h>
#include <hip/hip_bf16.h>
#include <stdint.h>

typedef __attribute__((ext_vector_type(8))) short bf16x8;
typedef __attribute__((ext_vector_type(4))) float f32x4;
typedef __attribute__((ext_vector_type(4))) unsigned short ushort4_t;

__device__ __forceinline__ unsigned short f2bf(float f) {
  union { float f; unsigned int i; } x; x.f = f;
  return (unsigned short)((x.i + 0x7fffu + ((x.i >> 16) & 1u)) >> 16);
}

// async global->LDS, 16B per lane; LDS dest is wave-uniform base + lane*16
__device__ __forceinline__ void gl_lds16(const void* g, void* l) {
  __builtin_amdgcn_global_load_lds(
      (const __attribute__((address_space(1))) unsigned int*)(uintptr_t)g,
      (__attribute__((address_space(3))) unsigned int*)(uint32_t)(uintptr_t)l,
      16, 0, 0);
}

// raw barrier (no vmcnt/lgkmcnt drain!) with compiler memory fences
__device__ __forceinline__ void bar() {
  asm volatile("" ::: "memory");
  __builtin_amdgcn_s_barrier();
  asm volatile("" ::: "memory");
}

// inv_freq[j] = 10000^(-j/16), j = 0..15 (d_half=32, 16 freqs)
__constant__ float INVF[16] = {
  1.0f,   0.56234132519f,  0.31622776601f,  0.17782794100f,
  0.1f,   0.056234132519f, 0.031622776601f, 0.017782794100f,
  0.01f,  0.0056234132519f,0.0031622776601f,0.0017782794100f,
  0.001f, 0.00056234132519f,0.00031622776601f,0.00017782794100f
};

// ---- fp32 -> bf16 bulk convert (x) ----
__global__ __launch_bounds__(256) void k_conv_x(const float4* __restrict__ src,
                                                ushort4_t* __restrict__ dst, int n4) {
  int i = blockIdx.x * 256 + threadIdx.x;
  if (i < n4) {
    float4 v = src[i];
    ushort4_t r = { f2bf(v.x), f2bf(v.y), f2bf(v.z), f2bf(v.w) };
    dst[i] = r;
  }
}

// ---- fp32 RxC -> bf16 CxR transpose (weights to B^T layout) ----
__global__ __launch_bounds__(256) void k_transpose_bf16(const float* __restrict__ src,
                                                        unsigned short* __restrict__ dst,
                                                        int R, int C) {
  __shared__ unsigned short tile[64][65];
  const int bj = blockIdx.x, bi = blockIdx.y;
  const int t = threadIdx.x, lr = t >> 6, lc = t & 63;
  #pragma unroll
  for (int i = 0; i < 16; i++) {
    int r = i * 4 + lr;
    tile[r][lc] = f2bf(src[(size_t)(bi * 64 + r) * C + bj * 64 + lc]);
  }
  __syncthreads();
  #pragma unroll
  for (int i = 0; i < 16; i++) {
    int r = i * 4 + lr;
    dst[(size_t)(bj * 64 + r) * R + bi * 64 + lc] = tile[lc][r];
  }
}

// ---- 8-phase pipelined GEMM (m201-class): C[M,N] = A[M,K]*B[N,K]^T ----
//
// BM=BN=256, BK=64, 512 threads = 8 waves (2M x 4N), 128x64 out/wave.
// LDS: 2 slots x (A 256x64 + B 256x64) = 128 KB; slot0=even tiles, slot1=odd.
// Iteration = 2 K-tiles = 8 phases. Phase = {ds-read quadrant subtile (0/4/8/12
// x b128) || stage 1 half-tile (2 x gl_lds) -> BAR -> lgkmcnt(0) -> setprio(1)
// -> 16 MFMA (one C-quadrant x K=64) -> setprio(0) -> BAR}. Counted vmcnt(4)
// only at phases 4 and 8 (= the 2 half-tiles staged in the current+prev phase
// stay in flight; everything older retired). Never drains mid-pipeline.
//
// Staging schedule (steady state, c even):
//   P1:(c+1)A0  P2:(c+1)A1  P3:(c+2)B0  P4:(c+2)B1 + vmcnt(4) [retires c+1 A]
//   P5:(c+2)A0  P6:(c+2)A1  P7:(c+3)B0  P8:(c+3)B1 + vmcnt(4) [retires c+2 all]
// Free-before-stage proof: slotX-B last ds_read issued in P2/P6 (bv1), retired
// at that phase's lgkmcnt(0), all waves joined at its trailing BAR before the
// stage issues in P3/P7. slotX-A last read in P3/P7 (af1) -> staged P5..P6/P1..P2.
// Cross-wave visibility: each wave's vmcnt(4) precedes a barrier; reads of the
// staged data happen >= 2 barriers later. Per-element MFMA order (kc0 then kc1
// per tile, tiles ascending) identical to previous rounds -> bitwise-same C.
//
// XOR chunk swizzle (LDS chunk t of row r holds global chunk t^(r&7) via
// pre-swizzled global source) -- conflict-free ds_read_b128, PMC-verified 0.
// XCD-aware bijective block swizzle kept (FETCH 303->193 MB, R4-verified).
// ROPE=1: fused 2D-RoPE epilogue on q/k cols (wave's 64-col group = 1 head).

#define LDA(dst, base, hm)                                                      \
  do {                                                                          \
    _Pragma("unroll") for (int t_ = 0; t_ < 4; t_++) {                          \
      dst[0][t_] = *(const bf16x8*)&base[(wm * 128 + (hm) * 64 + t_ * 16 + cl) * 64 + cf0]; \
      dst[1][t_] = *(const bf16x8*)&base[(wm * 128 + (hm) * 64 + t_ * 16 + cl) * 64 + cf1]; \
    }                                                                           \
  } while (0)

#define LDB(dst, base, hn)                                                      \
  do {                                                                          \
    _Pragma("unroll") for (int u_ = 0; u_ < 2; u_++) {                          \
      dst[0][u_] = *(const bf16x8*)&base[(wn * 64 + (hn) * 32 + u_ * 16 + cl) * 64 + cf0]; \
      dst[1][u_] = *(const bf16x8*)&base[(wn * 64 + (hn) * 32 + u_ * 16 + cl) * 64 + cf1]; \
    }                                                                           \
  } while (0)

#define MFMA_Q(hm, hn, AFR, BVR)                                                \
  do {                                                                          \
    __builtin_amdgcn_s_setprio(1);                                              \
    _Pragma("unroll") for (int kc_ = 0; kc_ < 2; kc_++)                         \
      _Pragma("unroll") for (int mt_ = 0; mt_ < 4; mt_++)                       \
        _Pragma("unroll") for (int u_ = 0; u_ < 2; u_++)                        \
          acc[(hm) * 4 + mt_][(hn) * 2 + u_] =                                  \
              __builtin_amdgcn_mfma_f32_16x16x32_bf16(                          \
                  AFR[kc_][mt_], BVR[kc_][u_],                                  \
                  acc[(hm) * 4 + mt_][(hn) * 2 + u_], 0, 0, 0);                 \
    __builtin_amdgcn_s_setprio(0);                                              \
  } while (0)

#define STAGE_A(tile_, half_)                                                   \
  do {                                                                          \
    const int so_ = ((tile_) & 1) * 16384;                                      \
    const int ko_ = (tile_) * 64;                                               \
    gl_lds16(aP[(half_) * 2] + ko_,     &As[so_ + ((half_) * 2) * 4096 + ldsW]);     \
    gl_lds16(aP[(half_) * 2 + 1] + ko_, &As[so_ + ((half_) * 2 + 1) * 4096 + ldsW]); \
  } while (0)

#define STAGE_B(tile_, half_)                                                   \
  do {                                                                          \
    const int so_ = ((tile_) & 1) * 16384;                                      \
    const int ko_ = (tile_) * 64;                                               \
    gl_lds16(bP[(half_) * 2] + ko_,     &Bs[so_ + ((half_) * 2) * 4096 + ldsW]);     \
    gl_lds16(bP[(half_) * 2 + 1] + ko_, &Bs[so_ + ((half_) * 2 + 1) * 4096 + ldsW]); \
  } while (0)

#define LGKM0() asm volatile("s_waitcnt lgkmcnt(0)" ::: "memory")
#define VMC(n)  asm volatile("s_waitcnt vmcnt(" #n ")" ::: "memory")

template<int F32OUT, int ROPE>
__global__ __launch_bounds__(512, 2) void k_gemm_bt(
    const unsigned short* __restrict__ A, const unsigned short* __restrict__ B,
    unsigned short* __restrict__ Cb, float* __restrict__ Cf,
    const float* __restrict__ bias, int M, int N, int K) {
  __shared__ __align__(16) unsigned short As[2 * 256 * 64];  // 64 KB
  __shared__ __align__(16) unsigned short Bs[2 * 256 * 64];  // 64 KB
  const int tid = threadIdx.x;
  const int lane = tid & 63, wid = tid >> 6;
  const int cl = lane & 15, gr = lane >> 4;
  const int wm = wid >> 2, wn = wid & 3;     // 2M x 4N wave grid
  const int l8 = lane >> 3, l7 = lane & 7;

  // XCD-aware bijective block swizzle (requires nwg % 8 == 0; holds here)
  const int gx = gridDim.x;
  const int nwg = gx * gridDim.y;
  const int fb = blockIdx.y * gx + blockIdx.x;
  const int q = nwg >> 3;
  const int nid = (fb & 7) * q + (fb >> 3);
  const int bx = nid % gx, by = nid / gx;
  const int mBase = by * 256, nBase = bx * 256;

  const int KT = K >> 6;                 // 64-wide K chunks (16 here; even)
  const int ldsW = (wid * 8) * 64;       // wave-uniform LDS row-base offset
  const int cf0 = ((0 * 4 + gr) ^ (cl & 7)) * 8;
  const int cf1 = ((1 * 4 + gr) ^ (cl & 7)) * 8;

  // per-thread global source pointers (include row and pre-swizzled chunk)
  const unsigned short* aP[4];
  const unsigned short* bP[4];
  #pragma unroll
  for (int i = 0; i < 4; i++) {
    aP[i] = A + (size_t)(mBase + i * 64 + wid * 8 + l8) * K + (l7 ^ l8) * 8;
    bP[i] = B + (size_t)(nBase + i * 64 + wid * 8 + l8) * K + (l7 ^ l8) * 8;
  }

  const f32x4 zero4 = {0.f, 0.f, 0.f, 0.f};
  f32x4 acc[8][4];
  #pragma unroll
  for (int a = 0; a < 8; a++)
    #pragma unroll
    for (int b = 0; b < 4; b++) acc[a][b] = zero4;

  // prologue: tile0 complete + tile1 B halves (12 gl_lds/wave)
  STAGE_A(0, 0); STAGE_A(0, 1); STAGE_B(0, 0); STAGE_B(0, 1);
  STAGE_B(1, 0); STAGE_B(1, 1);
  VMC(4);   // tile0 landed; tile1-B in flight
  bar();

  bf16x8 af[2][4], bva[2][2], bvb[2][2];

  for (int c = 0; c < KT; c += 2) {
    const unsigned short* a0 = As;           // slot0 (even tile c)
    const unsigned short* b0 = Bs;
    const unsigned short* a1 = As + 16384;   // slot1 (odd tile c+1)
    const unsigned short* b1 = Bs + 16384;
    const int c2 = c + 2, c3 = c + 3;

    // ---- tile c (slot0) ----
    // P1: quadrant (m0,n0)
    LDA(af, a0, 0); LDB(bva, b0, 0);
    STAGE_A(c + 1, 0);
    asm volatile("s_waitcnt lgkmcnt(8)" ::: "memory");
    bar(); LGKM0();
    MFMA_Q(0, 0, af, bva);
    bar();
    // P2: quadrant (m0,n1)
    LDB(bvb, b0, 1);
    STAGE_A(c + 1, 1);
    bar(); LGKM0();
    MFMA_Q(0, 1, af, bvb);
    bar();
    // P3: quadrant (m1,n1)
    LDA(af, a0, 1);
    if (c2 < KT) STAGE_B(c2, 0);
    bar(); LGKM0();
    MFMA_Q(1, 1, af, bvb);
    bar();
    // P4: quadrant (m1,n0); retire (c+1)-A, keep (c+2)-B in flight
    if (c2 < KT) { STAGE_B(c2, 1); VMC(4); } else { VMC(0); }
    bar();
    MFMA_Q(1, 0, af, bva);
    bar();

    // ---- tile c+1 (slot1) ----
    // P5
    LDA(af, a1, 0); LDB(bva, b1, 0);
    if (c2 < KT) STAGE_A(c2, 0);
    asm volatile("s_waitcnt lgkmcnt(8)" ::: "memory");
    bar(); LGKM0();
    MFMA_Q(0, 0, af, bva);
    bar();
    // P6
    LDB(bvb, b1, 1);
    if (c2 < KT) STAGE_A(c2, 1);
    bar(); LGKM0();
    MFMA_Q(0, 1, af, bvb);
    bar();
    // P7
    LDA(af, a1, 1);
    if (c3 < KT) STAGE_B(c3, 0);
    bar(); LGKM0();
    MFMA_Q(1, 1, af, bvb);
    bar();
    // P8: retire (c+2) fully, keep (c+3)-B in flight
    if (c3 < KT)      { STAGE_B(c3, 1); VMC(4); }
    else if (c2 < KT) { VMC(0); }
    bar();
    MFMA_Q(1, 0, af, bva);
    if (c2 < KT) bar();
  }

  if (ROPE && nBase < 2048) {  // q or k region of qkv output (wave-uniform)
    const float f2 = INVF[cl];
    #pragma unroll
    for (int amt = 0; amt < 8; amt++)
      #pragma unroll
      for (int r = 0; r < 4; r++) {
        const int sp = (mBase + wm * 128 + amt * 16 + gr * 4 + r) & 255;
        float sh, ch, sw, cw;
        __sincosf((float)(sp >> 4) * f2, &sh, &ch);
        __sincosf((float)(sp & 15) * f2, &sw, &cw);
        const float a = acc[amt][0][r], b = acc[amt][1][r];
        const float cc = acc[amt][2][r], d = acc[amt][3][r];
        acc[amt][0][r] = a * ch - b * sh;
        acc[amt][1][r] = b * ch + a * sh;
        acc[amt][2][r] = cc * cw - d * sw;
        acc[amt][3][r] = d * cw + cc * sw;
      }
  }

  // C/D layout (m89-verified): col = lane&15, row = (lane>>4)*4 + reg
  #pragma unroll
  for (int amt = 0; amt < 8; amt++)
    #pragma unroll
    for (int nt = 0; nt < 4; nt++)
      #pragma unroll
      for (int r = 0; r < 4; r++) {
        const int row = mBase + wm * 128 + amt * 16 + gr * 4 + r;
        const int col = nBase + wn * 64 + nt * 16 + cl;
        const float v = acc[amt][nt][r];
        if (F32OUT) Cf[(size_t)row * N + col] = v + bias[col];
        else        Cb[(size_t)row * N + col] = f2bf(v);
      }
}

// ---- flash attention (RoPE pre-applied): one block per (n, head); 4 waves x 64 q
// (unchanged this round -- GEMM 8-phase is the experiment; attn is next)
__global__ __launch_bounds__(256, 3) void k_attn(const unsigned short* __restrict__ qkv,
                                                 unsigned short* __restrict__ attn_out) {
  __shared__ __align__(16) unsigned short Qp[4][64 * 64];  // per-wave Q, then P
  __shared__ __align__(16) unsigned short Kt[64 * 64];
  __shared__ __align__(16) unsigned short Vt[64 * 64];     // V^T, pi-permuted cols
  const int blk = blockIdx.x;
  const int n = blk >> 4, h = blk & 15;
  const int tid = threadIdx.x;
  const int lane = tid & 63, wid = tid >> 6;
  const int cl = lane & 15, gr = lane >> 4;
  const int l8 = lane >> 3, l7 = lane & 7;
  const unsigned short* qbase = qkv + (size_t)n * 256 * 3072 + h * 64;
  const unsigned short* kbase = qbase + 1024;
  const unsigned short* vbase = qbase + 2048;

  #pragma unroll
  for (int i = 0; i < 8; i++)
    gl_lds16(qbase + (size_t)(wid * 64 + i * 8 + l8) * 3072 + (l7 ^ l8) * 8,
             &Qp[wid][i * 8 * 64]);
  #pragma unroll
  for (int i = 0; i < 2; i++) {
    const int r0 = (wid * 2 + i) * 8;
    gl_lds16(kbase + (size_t)(r0 + l8) * 3072 + (l7 ^ l8) * 8, &Kt[r0 * 64]);
  }

  unsigned int vr[2][4];
  #pragma unroll
  for (int i = 0; i < 2; i++) {
    const int u = i * 256 + tid;
    const int t0 = u >> 5, d = (u & 31) * 2;
    #pragma unroll
    for (int k = 0; k < 4; k++)
      vr[i][k] = *(const unsigned int*)(vbase + (size_t)(t0 + 16 * k) * 3072 + d);
  }
  __syncthreads();

  bf16x8 qf[4][2];
  #pragma unroll
  for (int mt = 0; mt < 4; mt++)
    #pragma unroll
    for (int kc = 0; kc < 2; kc++)
      qf[mt][kc] = *(const bf16x8*)&Qp[wid][(mt * 16 + cl) * 64 + ((kc * 4 + gr) ^ (cl & 7)) * 8];

  const f32x4 zero4 = {0.f, 0.f, 0.f, 0.f};
  f32x4 o[4][4];
  float lsum[4][4];
  #pragma unroll
  for (int a = 0; a < 4; a++)
    #pragma unroll
    for (int b = 0; b < 4; b++) { o[a][b] = zero4; lsum[a][b] = 0.f; }

  for (int tc = 0; tc < 4; tc++) {
    #pragma unroll
    for (int i = 0; i < 2; i++) {
      const int u = i * 256 + tid;
      const int t0 = u >> 5, d = (u & 31) * 2;
      const unsigned int r0 = vr[i][0], r1 = vr[i][1], r2 = vr[i][2], r3 = vr[i][3];
      uint2 lo, hi;
      lo.x = (r0 & 0xffffu) | (r1 << 16);
      lo.y = (r2 & 0xffffu) | (r3 << 16);
      hi.x = (r0 >> 16) | (r1 & 0xffff0000u);
      hi.y = (r2 >> 16) | (r3 & 0xffff0000u);
      *(uint2*)&Vt[d * 64 + ((t0 >> 1) ^ (d & 7)) * 8 + (t0 & 1) * 4] = lo;
      const int d1 = d + 1;
      *(uint2*)&Vt[d1 * 64 + ((t0 >> 1) ^ (d1 & 7)) * 8 + (t0 & 1) * 4] = hi;
    }
    if (tc < 3) {
      #pragma unroll
      for (int i = 0; i < 2; i++) {
        const int u = i * 256 + tid;
        const int t0 = u >> 5, d = (u & 31) * 2;
        #pragma unroll
        for (int k = 0; k < 4; k++)
          vr[i][k] = *(const unsigned int*)(vbase + (size_t)((tc + 1) * 64 + t0 + 16 * k) * 3072 + d);
      }
    }

    #pragma unroll
    for (int mt = 0; mt < 4; mt++) {
      f32x4 sacc[4] = {zero4, zero4, zero4, zero4};
      #pragma unroll
      for (int kc = 0; kc < 2; kc++)
        #pragma unroll
        for (int nt = 0; nt < 4; nt++) {
          const bf16x8 kf = *(const bf16x8*)&Kt[(nt * 16 + cl) * 64 + ((kc * 4 + gr) ^ (cl & 7)) * 8];
          sacc[nt] = __builtin_amdgcn_mfma_f32_16x16x32_bf16(qf[mt][kc], kf, sacc[nt], 0, 0, 0);
        }
      #pragma unroll
      for (int r = 0; r < 4; r++) {
        const float p0 = __expf(sacc[0][r] * 0.125f);
        const float p1 = __expf(sacc[1][r] * 0.125f);
        const float p2 = __expf(sacc[2][r] * 0.125f);
        const float p3 = __expf(sacc[3][r] * 0.125f);
        lsum[mt][r] += (p0 + p1) + (p2 + p3);
        float2 f01; f01.x = p0; f01.y = p1;
        float2 f23; f23.x = p2; f23.y = p3;
        __hip_bfloat162 b01 = __float22bfloat162_rn(f01);
        __hip_bfloat162 b23 = __float22bfloat162_rn(f23);
        union { __hip_bfloat162 h; unsigned int u; } c0, c1;
        c0.h = b01; c1.h = b23;
        uint2 w; w.x = c0.u; w.y = c1.u;
        const int m = mt * 16 + gr * 4 + r;
        *(uint2*)&Qp[wid][m * 64 + ((cl >> 1) ^ (m & 7)) * 8 + (cl & 1) * 4] = w;
      }
    }
    __syncthreads();

    if (tc < 3) {
      #pragma unroll
      for (int i = 0; i < 2; i++) {
        const int r0 = (wid * 2 + i) * 8;
        gl_lds16(kbase + (size_t)((tc + 1) * 64 + r0 + l8) * 3072 + (l7 ^ l8) * 8, &Kt[r0 * 64]);
      }
    }

    #pragma unroll
    for (int kc = 0; kc < 2; kc++) {
      bf16x8 vf[4], pf[4];
      #pragma unroll
      for (int dt = 0; dt < 4; dt++)
        vf[dt] = *(const bf16x8*)&Vt[(dt * 16 + cl) * 64 + ((kc * 4 + gr) ^ (cl & 7)) * 8];
      #pragma unroll
      for (int mt = 0; mt < 4; mt++)
        pf[mt] = *(const bf16x8*)&Qp[wid][(mt * 16 + cl) * 64 + ((kc * 4 + gr) ^ (cl & 7)) * 8];
      #pragma unroll
      for (int mt = 0; mt < 4; mt++)
        #pragma unroll
        for (int dt = 0; dt < 4; dt++)
          o[mt][dt] = __builtin_amdgcn_mfma_f32_16x16x32_bf16(pf[mt], vf[dt], o[mt][dt], 0, 0, 0);
    }
    __syncthreads();
  }

  #pragma unroll
  for (int mt = 0; mt < 4; mt++)
    #pragma unroll
    for (int r = 0; r < 4; r++) {
      float l = lsum[mt][r];
      l += __shfl_xor(l, 1);
      l += __shfl_xor(l, 2);
      l += __shfl_xor(l, 4);
      l += __shfl_xor(l, 8);
      const float inv = 1.0f / l;
      const int srow = wid * 64 + mt * 16 + gr * 4 + r;
      #pragma unroll
      for (int dt = 0; dt < 4; dt++)
        attn_out[(size_t)(n * 256 + srow) * 1024 + h * 64 + dt * 16 + cl] =
            f2bf(o[mt][dt][r] * inv);
    }
}

extern "C" void kernel_launch(void* const* d_in, const int* in_sizes, int n_in,
                              void* d_out, int out_size, void* d_ws, size_t ws_size,
                              hipStream_t stream) {
  const float* x      = (const float*)d_in[0];   // (4,32,16,16,1024)
  const float* w_qkv  = (const float*)d_in[1];   // (1024,3072)
  const float* w_proj = (const float*)d_in[2];   // (1024,1024)
  const float* b_proj = (const float*)d_in[3];   // (1024,)
  float* out = (float*)d_out;
  char* ws = (char*)d_ws;

  unsigned short* x_bf    = (unsigned short*)ws;                // 64 MiB (reused as attn out)
  unsigned short* wqkvT   = (unsigned short*)(ws + 67108864);   // [3072][1024]
  unsigned short* wprojT  = (unsigned short*)(ws + 73400320);   // [1024][1024]
  unsigned short* qkvb    = (unsigned short*)(ws + 75497472);   // [32768][3072]
  unsigned short* attn_bf = x_bf;

  k_conv_x<<<32768, 256, 0, stream>>>((const float4*)x, (ushort4_t*)x_bf, 8388608);
  k_transpose_bf16<<<dim3(48, 16), 256, 0, stream>>>(w_qkv, wqkvT, 1024, 3072);
  k_transpose_bf16<<<dim3(16, 16), 256, 0, stream>>>(w_proj, wprojT, 1024, 1024);

  // qkv = x @ w_qkv with fused 2D-RoPE on q,k (M=32768, N=3072, K=1024)
  k_gemm_bt<0, 1><<<dim3(12, 128), 512, 0, stream>>>(x_bf, wqkvT, qkvb, nullptr, nullptr,
                                                     32768, 3072, 1024);
  // flash attention, one block per (n, head)
  k_attn<<<2048, 256, 0, stream>>>(qkvb, attn_bf);

  // out = attn @ w_proj + b_proj (M=32768, N=1024, K=1024)
  k_gemm_bt<1, 0><<<dim3(4, 128), 512, 0, stream>>>(attn_bf, wprojT, nullptr, out, b_proj,
                                                    32768, 1024, 1024);
}